// Round 1
// 560.894 us; speedup vs baseline: 1.0473x; 1.0473x over previous
//
#include <hip/hip_runtime.h>

#define NU 50000
#define NI 100000
#define NT 150000
#define BB 4096
#define NBUCK 147   // ceil(NT/1024)
#define BCAP 24576  // per-bucket edge capacity: mean 21504, sd ~143 -> +21 sigma
#define NCH 8       // chunks per bucket in CSR build

typedef __attribute__((ext_vector_type(8))) short bf16x8;
typedef __attribute__((ext_vector_type(4))) float f32x4;
typedef __attribute__((ext_vector_type(2))) float f32x2;

__device__ __forceinline__ float softplusf(float x) {
  return fmaxf(x, 0.f) + log1pf(expf(-fabsf(x)));
}
__device__ __forceinline__ float wsum(float v) {
#pragma unroll
  for (int o = 32; o > 0; o >>= 1) v += __shfl_xor(v, o, 64);
  return v;
}
__device__ __forceinline__ float wmax(float v) {
#pragma unroll
  for (int o = 32; o > 0; o >>= 1) v = fmaxf(v, __shfl_xor(v, o, 64));
  return v;
}
__device__ __forceinline__ unsigned short f2b(float x) {
  unsigned u = __float_as_uint(x);
  return (unsigned short)((u + 0x7FFFu + ((u >> 16) & 1u)) >> 16);
}

// ---------------- CSR build ----------------
__global__ __launch_bounds__(256) void k_part(const int* __restrict__ h,
                                              const int* __restrict__ t,
                                              int* __restrict__ gcur,
                                              uint2* __restrict__ part, int E) {
  __shared__ int cnt[NBUCK];
  __shared__ int base[NBUCK];
  for (int b = threadIdx.x; b < NBUCK; b += 256) cnt[b] = 0;
  __syncthreads();
  int e0 = blockIdx.x * 4096 + threadIdx.x * 16;
  int nval = E - e0;
  nval = nval < 0 ? 0 : (nval > 16 ? 16 : nval);
  int hh[16], tt[16];
  if (nval == 16) {
    const int4* hp = (const int4*)(h + e0);
    const int4* tp = (const int4*)(t + e0);
#pragma unroll
    for (int j = 0; j < 4; j++) {
      int4 v = hp[j];
      hh[j * 4] = v.x; hh[j * 4 + 1] = v.y; hh[j * 4 + 2] = v.z; hh[j * 4 + 3] = v.w;
      int4 w = tp[j];
      tt[j * 4] = w.x; tt[j * 4 + 1] = w.y; tt[j * 4 + 2] = w.z; tt[j * 4 + 3] = w.w;
    }
  } else {
    for (int j = 0; j < nval; j++) { hh[j] = h[e0 + j]; tt[j] = t[e0 + j]; }
  }
  for (int j = 0; j < nval; j++) atomicAdd(&cnt[hh[j] >> 10], 1);
  __syncthreads();
  for (int b = threadIdx.x; b < NBUCK; b += 256) {
    int c = cnt[b];
    base[b] = c ? atomicAdd(&gcur[b], c) : 0;
    cnt[b] = 0;
  }
  __syncthreads();
  for (int j = 0; j < nval; j++) {
    int b = hh[j] >> 10;
    int r = atomicAdd(&cnt[b], 1);
    uint2 v; v.x = (unsigned)hh[j]; v.y = (unsigned)tt[j];
    part[(size_t)b * BCAP + base[b] + r] = v;
  }
}

// cnt_chunk layout: [(b<<10)+n][c] (node-major, chunk-minor) so k_node's
// 8-chunk loop is 32B contiguous.
__global__ __launch_bounds__(256) void k_count2(const uint2* __restrict__ part,
                                                const int* __restrict__ gcur,
                                                int* __restrict__ cnt_chunk) {
  __shared__ int hist[1024];
  int b = blockIdx.x, c = blockIdx.y, tid = threadIdx.x;
  for (int i = tid; i < 1024; i += 256) hist[i] = 0;
  __syncthreads();
  int m = gcur[b];
  int lo = (int)(((long long)m * c) >> 3);
  int hi = (int)(((long long)m * (c + 1)) >> 3);
  const uint2* pp = part + (size_t)b * BCAP;
  for (int i = lo + tid; i < hi; i += 256) atomicAdd(&hist[pp[i].x & 1023], 1);
  __syncthreads();
  for (int i = tid; i < 1024; i += 256)
    cnt_chunk[((((size_t)b << 10) + i) << 3) + c] = hist[i];
}

// No x16 padding anymore: row_ptr is the EXACT CSR (k_agg masks the tail
// lanes instead), which kills the 44MB edges memset and shrinks edge reads.
__global__ __launch_bounds__(256) void k_node(int* __restrict__ cnt_chunk,
                                              int* __restrict__ rloc_g,
                                              float* __restrict__ d_inv,
                                              int* __restrict__ btot) {
  __shared__ int sd[256];
  int b = blockIdx.x, tid = threadIdx.x;
  int n0 = b << 10;
  int pd[4];
  int s = 0;
#pragma unroll
  for (int j = 0; j < 4; j++) {
    int idx = tid * 4 + j;
    size_t base = ((size_t)(n0 + idx)) << 3;
    int run = 0;
#pragma unroll
    for (int c = 0; c < NCH; c++) {
      int v = cnt_chunk[base + c];
      cnt_chunk[base + c] = run;
      run += v;
    }
    int n = n0 + idx;
    if (n < NT) {
      d_inv[n] = 1.0f / sqrtf((float)run);  // deg >= 1 (self-loop)
      pd[j] = run;
    } else pd[j] = 0;
    s += pd[j];
  }
  sd[tid] = s;
  __syncthreads();
  for (int o = 1; o < 256; o <<= 1) {
    int x = (tid >= o) ? sd[tid - o] : 0;
    __syncthreads();
    sd[tid] += x;
    __syncthreads();
  }
  int run2 = sd[tid] - s;
#pragma unroll
  for (int j = 0; j < 4; j++) {
    int idx = tid * 4 + j, n = n0 + idx;
    if (n < NT) rloc_g[n] = run2;
    run2 += pd[j];
  }
  if (tid == 255) btot[b] = sd[255];
}

// merged: per-block redundant scan of 147 bucket totals + row_ptr write
__global__ __launch_bounds__(256) void k_rowptr(const int* __restrict__ btot,
                                                const int* __restrict__ rloc_g,
                                                int* __restrict__ row_ptr) {
  __shared__ int sd[256];
  __shared__ int ex[256];
  int t = threadIdx.x;
  int v = (t < NBUCK) ? btot[t] : 0;
  sd[t] = v;
  __syncthreads();
  for (int o = 1; o < 256; o <<= 1) {
    int x = (t >= o) ? sd[t - o] : 0;
    __syncthreads();
    sd[t] += x;
    __syncthreads();
  }
  ex[t] = sd[t] - v;
  __syncthreads();
  int n = blockIdx.x * 256 + t;
  if (n < NT) row_ptr[n] = ex[n >> 10] + rloc_g[n];
  if (blockIdx.x == 0 && t == 0) row_ptr[NT] = sd[NBUCK - 1];
}

__global__ __launch_bounds__(256) void k_fill2(const uint2* __restrict__ part,
                                               const int* __restrict__ gcur,
                                               const int* __restrict__ chunkpre,
                                               const int* __restrict__ row_ptr,
                                               const float* __restrict__ d_inv,
                                               uint2* __restrict__ edges) {
  __shared__ int curs[1024];
  __shared__ float dl[1024];
  int b = blockIdx.x, c = blockIdx.y, tid = threadIdx.x;
  int n0 = b << 10;
  for (int i = tid; i < 1024; i += 256) {
    int n = n0 + i;
    if (n < NT) {
      curs[i] = row_ptr[n] + chunkpre[((((size_t)b << 10) + i) << 3) + c];
      dl[i] = d_inv[n];
    }
  }
  __syncthreads();
  int m = gcur[b];
  int lo = (int)(((long long)m * c) >> 3);
  int hi = (int)(((long long)m * (c + 1)) >> 3);
  const uint2* pp = part + (size_t)b * BCAP;
  for (int i = lo + tid; i < hi; i += 256) {
    uint2 pe = pp[i];
    int slot = atomicAdd(&curs[pe.x & 1023], 1);
    float g = dl[pe.x & 1023] * d_inv[pe.y];
    uint2 v; v.x = pe.y; v.y = __float_as_uint(g);
    edges[slot] = v;
  }
}

// ---------------- propagation ----------------
// cur/nxt rows: 64 fp8(e4m3) dims packed as 16 dwords -> 64B row, ONE line
// per edge, FOUR rows per wave64 dword-gather.
__global__ void k_init(const float4* __restrict__ ue, const float4* __restrict__ ie,
                       unsigned* __restrict__ cur, int nU4, int nTot4) {
  int i = blockIdx.x * 256 + threadIdx.x;
  if (i >= nTot4) return;
  float4 v = (i < nU4) ? ue[i] : ie[i - nU4];
  int p = __builtin_amdgcn_cvt_pk_fp8_f32(v.x, v.y, 0, false);
  p = __builtin_amdgcn_cvt_pk_fp8_f32(v.z, v.w, p, true);
  cur[i] = (unsigned)p;
}

// wave = 4 quarter-groups; lane = (g = edge-group 0..3, d = dword 0..15).
// Round 14: the wave is LATENCY-bound (avg degree ~22 -> only ~2 serial
// chains rec->shfl->gather->fma per wave). Unroll to 32 edges/iter so ~99%
// of nodes finish in ONE chain: 2 rec loads + 8 gathers in flight together.
// Tail lanes are masked (clamp index, g=0) instead of padded CSR slots.
// NOTE: flat named registers only — register ARRAYS here spill (round 7).
__global__ __launch_bounds__(256) void k_agg(const int* __restrict__ row_ptr,
                                             const uint2* __restrict__ edges,
                                             const unsigned* __restrict__ cur,
                                             unsigned* __restrict__ nxt,
                                             float4* __restrict__ acc4,
                                             const float4* __restrict__ egoU,
                                             const float4* __restrict__ egoI,
                                             int first, int last) {
  int node = (blockIdx.x << 2) + (threadIdx.x >> 6);
  unsigned lane = threadIdx.x & 63;
  unsigned d = lane & 15;
  unsigned g = lane >> 4;
  int b4 = (int)(g << 2);
  int s = row_ptr[node], e = row_ptr[node + 1];
  float a0 = 0.f, a1 = 0.f, a2 = 0.f, a3 = 0.f;
  for (int i = s; i < e; i += 32) {
    int ia = i + (int)d;
    int ib = ia + 16;
    uint2 ra = edges[ia < e ? ia : e - 1];
    uint2 rb = edges[ib < e ? ib : e - 1];
    unsigned rya = (ia < e) ? ra.y : 0u;
    unsigned ryb = (ib < e) ? rb.y : 0u;
    unsigned iA0 = __shfl(ra.x, b4 + 0, 64); float gA0 = __uint_as_float(__shfl(rya, b4 + 0, 64));
    unsigned iA1 = __shfl(ra.x, b4 + 1, 64); float gA1 = __uint_as_float(__shfl(rya, b4 + 1, 64));
    unsigned iA2 = __shfl(ra.x, b4 + 2, 64); float gA2 = __uint_as_float(__shfl(rya, b4 + 2, 64));
    unsigned iA3 = __shfl(ra.x, b4 + 3, 64); float gA3 = __uint_as_float(__shfl(rya, b4 + 3, 64));
    unsigned vA0 = cur[(iA0 << 4) + d];
    unsigned vA1 = cur[(iA1 << 4) + d];
    unsigned vA2 = cur[(iA2 << 4) + d];
    unsigned vA3 = cur[(iA3 << 4) + d];
    unsigned iB0 = __shfl(rb.x, b4 + 0, 64); float gB0 = __uint_as_float(__shfl(ryb, b4 + 0, 64));
    unsigned iB1 = __shfl(rb.x, b4 + 1, 64); float gB1 = __uint_as_float(__shfl(ryb, b4 + 1, 64));
    unsigned iB2 = __shfl(rb.x, b4 + 2, 64); float gB2 = __uint_as_float(__shfl(ryb, b4 + 2, 64));
    unsigned iB3 = __shfl(rb.x, b4 + 3, 64); float gB3 = __uint_as_float(__shfl(ryb, b4 + 3, 64));
    unsigned vB0 = cur[(iB0 << 4) + d];
    unsigned vB1 = cur[(iB1 << 4) + d];
    unsigned vB2 = cur[(iB2 << 4) + d];
    unsigned vB3 = cur[(iB3 << 4) + d];
    f32x2 lo, hi;
    lo = __builtin_amdgcn_cvt_pk_f32_fp8(vA0, false);
    hi = __builtin_amdgcn_cvt_pk_f32_fp8(vA0, true);
    a0 = fmaf(gA0, lo.x, a0); a1 = fmaf(gA0, lo.y, a1);
    a2 = fmaf(gA0, hi.x, a2); a3 = fmaf(gA0, hi.y, a3);
    lo = __builtin_amdgcn_cvt_pk_f32_fp8(vA1, false);
    hi = __builtin_amdgcn_cvt_pk_f32_fp8(vA1, true);
    a0 = fmaf(gA1, lo.x, a0); a1 = fmaf(gA1, lo.y, a1);
    a2 = fmaf(gA1, hi.x, a2); a3 = fmaf(gA1, hi.y, a3);
    lo = __builtin_amdgcn_cvt_pk_f32_fp8(vA2, false);
    hi = __builtin_amdgcn_cvt_pk_f32_fp8(vA2, true);
    a0 = fmaf(gA2, lo.x, a0); a1 = fmaf(gA2, lo.y, a1);
    a2 = fmaf(gA2, hi.x, a2); a3 = fmaf(gA2, hi.y, a3);
    lo = __builtin_amdgcn_cvt_pk_f32_fp8(vA3, false);
    hi = __builtin_amdgcn_cvt_pk_f32_fp8(vA3, true);
    a0 = fmaf(gA3, lo.x, a0); a1 = fmaf(gA3, lo.y, a1);
    a2 = fmaf(gA3, hi.x, a2); a3 = fmaf(gA3, hi.y, a3);
    lo = __builtin_amdgcn_cvt_pk_f32_fp8(vB0, false);
    hi = __builtin_amdgcn_cvt_pk_f32_fp8(vB0, true);
    a0 = fmaf(gB0, lo.x, a0); a1 = fmaf(gB0, lo.y, a1);
    a2 = fmaf(gB0, hi.x, a2); a3 = fmaf(gB0, hi.y, a3);
    lo = __builtin_amdgcn_cvt_pk_f32_fp8(vB1, false);
    hi = __builtin_amdgcn_cvt_pk_f32_fp8(vB1, true);
    a0 = fmaf(gB1, lo.x, a0); a1 = fmaf(gB1, lo.y, a1);
    a2 = fmaf(gB1, hi.x, a2); a3 = fmaf(gB1, hi.y, a3);
    lo = __builtin_amdgcn_cvt_pk_f32_fp8(vB2, false);
    hi = __builtin_amdgcn_cvt_pk_f32_fp8(vB2, true);
    a0 = fmaf(gB2, lo.x, a0); a1 = fmaf(gB2, lo.y, a1);
    a2 = fmaf(gB2, hi.x, a2); a3 = fmaf(gB2, hi.y, a3);
    lo = __builtin_amdgcn_cvt_pk_f32_fp8(vB3, false);
    hi = __builtin_amdgcn_cvt_pk_f32_fp8(vB3, true);
    a0 = fmaf(gB3, lo.x, a0); a1 = fmaf(gB3, lo.y, a1);
    a2 = fmaf(gB3, hi.x, a2); a3 = fmaf(gB3, hi.y, a3);
  }
  a0 += __shfl_xor(a0, 16, 64);
  a1 += __shfl_xor(a1, 16, 64);
  a2 += __shfl_xor(a2, 16, 64);
  a3 += __shfl_xor(a3, 16, 64);
  a0 += __shfl_xor(a0, 32, 64);
  a1 += __shfl_xor(a1, 32, 64);
  a2 += __shfl_xor(a2, 32, 64);
  a3 += __shfl_xor(a3, 32, 64);
  unsigned ro = ((unsigned)node << 4) + d;
  if (g == 0) {
    float4 base;
    if (first) {
      base = (node < NU) ? egoU[ro] : egoI[ro - (unsigned)NU * 16u];
    } else {
      base = acc4[ro];
    }
    base.x += a0;
    base.y += a1;
    base.z += a2;
    base.w += a3;
    acc4[ro] = base;
  } else if (g == 1 && !last) {
    int p = __builtin_amdgcn_cvt_pk_fp8_f32(a0, a1, 0, false);
    p = __builtin_amdgcn_cvt_pk_fp8_f32(a2, a3, p, true);
    nxt[ro] = (unsigned)p;
  }
}

// ---------------- losses ----------------
// KL via MFMA; grid-stride + one atomic per block (round 11: per-wave
// same-address double atomics serialized at ~31 cy = 121 us wall).
__global__ __launch_bounds__(256) void k_kl(const float* __restrict__ acc,
                                            const float* __restrict__ lin_w,
                                            const float* __restrict__ lin_b,
                                            double* __restrict__ accums) {
  __shared__ double red[4];
  int lane = threadIdx.x & 63;
  int wid = threadIdx.x >> 6;
  int n = lane & 15, q = lane >> 4;
  bf16x8 B0, B1, B2, B3;
  float lb0, lb1, lb2, lb3;
  {
    const float* w0 = lin_w + (0 * 16 + n) * 32 + q * 8;
    const float* w1 = lin_w + (1 * 16 + n) * 32 + q * 8;
    const float* w2 = lin_w + (2 * 16 + n) * 32 + q * 8;
    const float* w3 = lin_w + (3 * 16 + n) * 32 + q * 8;
#pragma unroll
    for (int j = 0; j < 8; j++) {
      B0[j] = (short)f2b(w0[j]);
      B1[j] = (short)f2b(w1[j]);
      B2[j] = (short)f2b(w2[j]);
      B3[j] = (short)f2b(w3[j]);
    }
    lb0 = lin_b[0 * 16 + n] + 1e-8f;
    lb1 = lin_b[1 * 16 + n] + 1e-8f;
    lb2 = lin_b[2 * 16 + n] + 1e-8f;
    lb3 = lin_b[3 * 16 + n] + 1e-8f;
  }
  const int TI = NT / 16;
  int w0id = blockIdx.x * 4 + wid;
  int nwv = gridDim.x * 4;
  double dsum = 0.0;
  for (int tile = w0id; tile < TI; tile += nwv) {
    const float* rowp = acc + (size_t)(tile * 16 + n) * 64 + q * 8;
    float4 a0 = *(const float4*)rowp;
    float4 a1 = *(const float4*)(rowp + 4);
    float4 b0 = *(const float4*)(rowp + 32);
    float4 b1 = *(const float4*)(rowp + 36);
    float msum = a0.x * a0.x + a0.y * a0.y + a0.z * a0.z + a0.w * a0.w
               + a1.x * a1.x + a1.y * a1.y + a1.z * a1.z + a1.w * a1.w
               + b0.x * b0.x + b0.y * b0.y + b0.z * b0.z + b0.w * b0.w
               + b1.x * b1.x + b1.y * b1.y + b1.z * b1.z + b1.w * b1.w;
    bf16x8 Af;
    Af[0] = (short)f2b(softplusf(a0.x));
    Af[1] = (short)f2b(softplusf(a0.y));
    Af[2] = (short)f2b(softplusf(a0.z));
    Af[3] = (short)f2b(softplusf(a0.w));
    Af[4] = (short)f2b(softplusf(a1.x));
    Af[5] = (short)f2b(softplusf(a1.y));
    Af[6] = (short)f2b(softplusf(a1.z));
    Af[7] = (short)f2b(softplusf(a1.w));
    f32x4 z = {0.f, 0.f, 0.f, 0.f};
    f32x4 c0 = __builtin_amdgcn_mfma_f32_16x16x32_bf16(Af, B0, z, 0, 0, 0);
    f32x4 c1 = __builtin_amdgcn_mfma_f32_16x16x32_bf16(Af, B1, z, 0, 0, 0);
    f32x4 c2 = __builtin_amdgcn_mfma_f32_16x16x32_bf16(Af, B2, z, 0, 0, 0);
    f32x4 c3 = __builtin_amdgcn_mfma_f32_16x16x32_bf16(Af, B3, z, 0, 0, 0);
    float ksum = 0.f;
#pragma unroll
    for (int r = 0; r < 4; r++) {
      float s0 = c0[r] + lb0, s1 = c1[r] + lb1, s2 = c2[r] + lb2, s3 = c3[r] + lb3;
      ksum += -0.5f * (1.f + 2.f * s0 - __expf(2.f * s0));
      ksum += -0.5f * (1.f + 2.f * s1 - __expf(2.f * s1));
      ksum += -0.5f * (1.f + 2.f * s2 - __expf(2.f * s2));
      ksum += -0.5f * (1.f + 2.f * s3 - __expf(2.f * s3));
    }
    dsum += (double)wsum(ksum + 0.5f * msum);
  }
  if (lane == 0) red[wid] = dsum;
  __syncthreads();
  if (threadIdx.x == 0)
    atomicAdd(&accums[1], red[0] + red[1] + red[2] + red[3]);
}

__global__ __launch_bounds__(256) void k_batch_user(
    const float* __restrict__ acc, const float* __restrict__ user_emb,
    const float* __restrict__ eps, const float* __restrict__ intent,
    const float* __restrict__ lin_w, const float* __restrict__ lin_b,
    const int* __restrict__ users, const int* __restrict__ pos_items,
    const int* __restrict__ neg_items,
    float* __restrict__ gen_o, float* __restrict__ int_o,
    unsigned short* __restrict__ gen_b, unsigned short* __restrict__ int_b,
    double* __restrict__ accums) {
  __shared__ float ui[64 * 130];
  __shared__ float lw[64 * 33];
  __shared__ float lb[64];
  __shared__ double red[8];
  for (int i = threadIdx.x; i < 64 * 128; i += 256) ui[(i >> 7) * 130 + (i & 127)] = intent[i];
  for (int i = threadIdx.x; i < 64 * 32; i += 256) lw[(i >> 5) * 33 + (i & 31)] = lin_w[i];
  if (threadIdx.x < 64) lb[threadIdx.x] = lin_b[threadIdx.x];
  __syncthreads();
  int lane = threadIdx.x & 63;
  int wid = threadIdx.x >> 6;
  int b = (blockIdx.x << 2) + wid;
  int u = users[b];
  float m = acc[u * 64 + lane];
  int k0 = lane * 2;
  float l0 = 0.f, l1 = 0.f;
  for (int d = 0; d < 64; d++) {
    float md = __shfl(m, d, 64);
    l0 = fmaf(md, ui[d * 130 + k0], l0);
    l1 = fmaf(md, ui[d * 130 + k0 + 1], l1);
  }
  float mx = wmax(fmaxf(l0, l1));
  float p0 = expf(l0 - mx), p1 = expf(l1 - mx);
  float tot = wsum(p0 + p1);
  p0 /= tot; p1 /= tot;
  float s = 0.f;
  for (int k = 0; k < 128; k++) {
    float pk = __shfl((k & 1) ? p1 : p0, k >> 1, 64);
    s = fmaf(pk, ui[lane * 130 + k], s);
  }
  float nrm = sqrtf(wsum(s * s));
  float io = s / nrm;
  int_o[b * 64 + lane] = io;
  int_b[b * 64 + lane] = f2b(io);
  float sp = softplusf(m);
  float sd = lb[lane] + 1e-8f;
#pragma unroll
  for (int j = 0; j < 32; j++) sd = fmaf(__shfl(sp, j, 64), lw[lane * 33 + j], sd);
  float ge = m + eps[u * 64 + lane] * sd;
  float gn = sqrtf(wsum(ge * ge));
  float go = ge / gn;
  gen_o[b * 64 + lane] = go;
  gen_b[b * 64 + lane] = f2b(go);
  int pi = pos_items[b], ni = neg_items[b];
  float pv = acc[(NU + pi) * 64 + lane];
  float nv = acc[(NU + ni) * 64 + lane];
  float ps = wsum(m * pv);
  float ns = wsum(m * nv);
  float bpr = softplusf(ns - ps);
  float ue = user_emb[u * 64 + lane];
  float es = wsum(ue * ue);
  if (lane == 0) { red[wid] = (double)bpr; red[4 + wid] = (double)es; }
  __syncthreads();
  if (threadIdx.x == 0) {
    atomicAdd(&accums[0], red[0] + red[1] + red[2] + red[3]);
    atomicAdd(&accums[2], red[4] + red[5] + red[6] + red[7]);
  }
}

__global__ __launch_bounds__(256) void k_batch_item(
    const float* __restrict__ acc, const float* __restrict__ item_emb,
    const float* __restrict__ eps, const float* __restrict__ intent,
    const float* __restrict__ lin_w, const float* __restrict__ lin_b,
    const int* __restrict__ pos_items, const int* __restrict__ neg_items,
    float* __restrict__ gen_o, float* __restrict__ int_o,
    unsigned short* __restrict__ gen_b, unsigned short* __restrict__ int_b,
    double* __restrict__ accums) {
  __shared__ float ui[64 * 130];
  __shared__ float lw[64 * 33];
  __shared__ float lb[64];
  __shared__ double red[4];
  for (int i = threadIdx.x; i < 64 * 128; i += 256) ui[(i >> 7) * 130 + (i & 127)] = intent[i];
  for (int i = threadIdx.x; i < 64 * 32; i += 256) lw[(i >> 5) * 33 + (i & 31)] = lin_w[i];
  if (threadIdx.x < 64) lb[threadIdx.x] = lin_b[threadIdx.x];
  __syncthreads();
  int lane = threadIdx.x & 63;
  int wid = threadIdx.x >> 6;
  int b = (blockIdx.x << 2) + wid;
  int pi = pos_items[b], ni = neg_items[b];
  int row = NU + pi;
  float m = acc[row * 64 + lane];
  int k0 = lane * 2;
  float l0 = 0.f, l1 = 0.f;
  for (int d = 0; d < 64; d++) {
    float md = __shfl(m, d, 64);
    l0 = fmaf(md, ui[d * 130 + k0], l0);
    l1 = fmaf(md, ui[d * 130 + k0 + 1], l1);
  }
  float mx = wmax(fmaxf(l0, l1));
  float p0 = expf(l0 - mx), p1 = expf(l1 - mx);
  float tot = wsum(p0 + p1);
  p0 /= tot; p1 /= tot;
  float s = 0.f;
  for (int k = 0; k < 128; k++) {
    float pk = __shfl((k & 1) ? p1 : p0, k >> 1, 64);
    s = fmaf(pk, ui[lane * 130 + k], s);
  }
  float nrm = sqrtf(wsum(s * s));
  float io = s / nrm;
  int_o[b * 64 + lane] = io;
  int_b[b * 64 + lane] = f2b(io);
  float sp = softplusf(m);
  float sd = lb[lane] + 1e-8f;
#pragma unroll
  for (int j = 0; j < 32; j++) sd = fmaf(__shfl(sp, j, 64), lw[lane * 33 + j], sd);
  float ge = m + eps[row * 64 + lane] * sd;
  float gn = sqrtf(wsum(ge * ge));
  float go = ge / gn;
  gen_o[b * 64 + lane] = go;
  gen_b[b * 64 + lane] = f2b(go);
  float a0 = item_emb[pi * 64 + lane];
  float a1 = item_emb[ni * 64 + lane];
  float es = wsum(a0 * a0 + a1 * a1);
  if (lane == 0) red[wid] = (double)es;
  __syncthreads();
  if (threadIdx.x == 0) atomicAdd(&accums[2], red[0] + red[1] + red[2] + red[3]);
}

// ---------------- InfoNCE negatives via bf16 MFMA ----------------
__global__ __launch_bounds__(256) void k_nce_mfma(
    const unsigned short* __restrict__ e1u, const unsigned short* __restrict__ e2u,
    const unsigned short* __restrict__ e1i, const unsigned short* __restrict__ e2i,
    float* __restrict__ negu, float* __restrict__ negi) {
  int pair = blockIdx.y >> 2, jq = blockIdx.y & 3;
  const unsigned short* e1 = pair ? e1i : e1u;
  const unsigned short* e2 = pair ? e2i : e2u;
  float* nego = pair ? negi : negu;
  int wid = threadIdx.x >> 6, lane = threadIdx.x & 63;
  int q = lane >> 4, n = lane & 15;
  int i0 = blockIdx.x * 64 + wid * 16;
  const bf16x8* arow = (const bf16x8*)(e1 + (size_t)(i0 + n) * 64 + q * 8);
  bf16x8 a0 = arow[0];
  bf16x8 a1 = arow[4];
  f32x4 accv = {0.f, 0.f, 0.f, 0.f};
  int j0 = jq * 1024;
  for (int jt = 0; jt < 64; jt++) {
    const bf16x8* brow = (const bf16x8*)(e2 + (size_t)(j0 + jt * 16 + n) * 64 + q * 8);
    bf16x8 b0 = brow[0];
    bf16x8 b1 = brow[4];
    f32x4 c = {0.f, 0.f, 0.f, 0.f};
    c = __builtin_amdgcn_mfma_f32_16x16x32_bf16(a0, b0, c, 0, 0, 0);
    c = __builtin_amdgcn_mfma_f32_16x16x32_bf16(a1, b1, c, 0, 0, 0);
#pragma unroll
    for (int r = 0; r < 4; r++) accv[r] += __expf(5.0f * c[r]);
  }
#pragma unroll
  for (int o = 1; o < 16; o <<= 1) {
#pragma unroll
    for (int r = 0; r < 4; r++) accv[r] += __shfl_xor(accv[r], o, 64);
  }
  if (n == 0) {
#pragma unroll
    for (int r = 0; r < 4; r++) atomicAdd(&nego[i0 + q * 4 + r], accv[r]);
  }
}

__global__ __launch_bounds__(256) void k_nce_final(
    const float* __restrict__ ugen, const float* __restrict__ uio,
    const float* __restrict__ igen, const float* __restrict__ iio,
    const float* __restrict__ negu, const float* __restrict__ negi,
    double* __restrict__ accums) {
  __shared__ double red[4];
  int lane = threadIdx.x & 63, wid = threadIdx.x >> 6;
  int w = blockIdx.x * 4 + wid;
  int pair = w >> 12, i = w & 4095;
  const float* e1 = pair ? igen : ugen;
  const float* e2 = pair ? iio : uio;
  const float* ng = pair ? negi : negu;
  float dot = wsum(e1[i * 64 + lane] * e2[i * 64 + lane]);
  if (lane == 0) {
    float pos = expf(dot * 5.f);
    red[wid] = (double)(-logf(pos / (ng[i] + 1e-8f) + 1e-8f));
  }
  __syncthreads();
  if (threadIdx.x == 0) atomicAdd(&accums[4], red[0] + red[1] + red[2] + red[3]);
}

// final: also folds the tiny int_loss reduction
__global__ __launch_bounds__(256) void k_fin(const float* __restrict__ ui,
                                             const float* __restrict__ ii,
                                             const double* __restrict__ accums,
                                             float* __restrict__ out) {
  __shared__ float red[4];
  float s = 0.f;
  for (int i = threadIdx.x; i < 64 * 128; i += 256) {
    float a = ui[i], b = ii[i];
    s = fmaf(a, a, s);
    s = fmaf(b, b, s);
  }
  s = wsum(s);
  if ((threadIdx.x & 63) == 0) red[threadIdx.x >> 6] = s;
  __syncthreads();
  if (threadIdx.x == 0) {
    double ints = (double)(red[0] + red[1] + red[2] + red[3]);
    double bpr = accums[0] / (double)BB;
    double kl = 0.01 * accums[1] / (double)NT;
    out[0] = (float)(bpr + kl);
    out[1] = (float)(0.1 * accums[4] / (double)BB);
    out[2] = (float)(1e-5 * accums[2]);
    out[3] = (float)(1e-5 * ints);
  }
}

extern "C" void kernel_launch(void* const* d_in, const int* in_sizes, int n_in,
                              void* d_out, int out_size, void* d_ws, size_t ws_size,
                              hipStream_t stream) {
  const float* user_emb = (const float*)d_in[0];
  const float* item_emb = (const float*)d_in[1];
  const float* user_int = (const float*)d_in[2];
  const float* item_int = (const float*)d_in[3];
  const float* lin_w = (const float*)d_in[4];
  const float* lin_b = (const float*)d_in[5];
  const float* eps = (const float*)d_in[6];
  const int* h_list = (const int*)d_in[7];
  const int* t_list = (const int*)d_in[8];
  const int* users = (const int*)d_in[9];
  const int* pos_items = (const int*)d_in[10];
  const int* neg_items = (const int*)d_in[11];
  float* out = (float*)d_out;
  const int E = in_sizes[7];

  char* ws = (char*)d_ws;
  size_t off = 0;
  auto take = [&](size_t bytes) -> char* {
    char* p = ws + off;
    off = (off + bytes + 255) & ~(size_t)255;
    return p;
  };
  int* row_ptr = (int*)take((size_t)(NT + 1) * 4);
  float* d_inv = (float*)take((size_t)NT * 4);
  int* rloc_g = (int*)take((size_t)NT * 4);
  int* cnt_chunk = (int*)take((size_t)NBUCK * NCH * 1024 * 4);
  int* gcur = (int*)take(NBUCK * 4);
  int* btot = (int*)take(NBUCK * 4);
  uint2* edges = (uint2*)take((size_t)E * 8);
  unsigned* bufA = (unsigned*)take((size_t)NT * 16 * 4);  // fp8 rows (16 dwords)
  unsigned* bufB = (unsigned*)take((size_t)NT * 16 * 4);
  float* acc = (float*)take((size_t)NT * 64 * 4);
  float* ugen = (float*)take((size_t)BB * 64 * 4);
  float* igen = (float*)take((size_t)BB * 64 * 4);
  float* uio = (float*)take((size_t)BB * 64 * 4);
  float* iio = (float*)take((size_t)BB * 64 * 4);
  unsigned short* ugen_b = (unsigned short*)take((size_t)BB * 64 * 2);
  unsigned short* igen_b = (unsigned short*)take((size_t)BB * 64 * 2);
  unsigned short* uio_b = (unsigned short*)take((size_t)BB * 64 * 2);
  unsigned short* iio_b = (unsigned short*)take((size_t)BB * 64 * 2);
  float* negu = (float*)take((size_t)BB * 4);
  float* negi = (float*)take((size_t)BB * 4);
  double* accums = (double*)take(64);
  if (off > ws_size) return;
  // part[] (28.9 MB) aliases acc (38.4 MB): part's last read is k_fill2;
  // acc is first WRITTEN in k_agg#1 (first=1 -> no acc read).
  uint2* part = (uint2*)acc;

  hipMemsetAsync(gcur, 0, NBUCK * 4, stream);
  hipMemsetAsync(negu, 0, (size_t)BB * 4, stream);
  hipMemsetAsync(negi, 0, (size_t)BB * 4, stream);
  hipMemsetAsync(accums, 0, 64, stream);

  int gridP = (E + 4095) / 4096;
  k_part<<<gridP, 256, 0, stream>>>(h_list, t_list, gcur, part, E);
  k_count2<<<dim3(NBUCK, NCH), 256, 0, stream>>>(part, gcur, cnt_chunk);
  k_node<<<NBUCK, 256, 0, stream>>>(cnt_chunk, rloc_g, d_inv, btot);
  k_rowptr<<<(NT + 255) / 256, 256, 0, stream>>>(btot, rloc_g, row_ptr);
  k_fill2<<<dim3(NBUCK, NCH), 256, 0, stream>>>(part, gcur, cnt_chunk, row_ptr,
                                                d_inv, edges);

  int nU4 = NU * 16, nTot4 = NT * 16;
  k_init<<<(nTot4 + 255) / 256, 256, 0, stream>>>((const float4*)user_emb,
                                                  (const float4*)item_emb, bufA, nU4, nTot4);
  int gridAgg = NT / 4;
  k_agg<<<gridAgg, 256, 0, stream>>>(row_ptr, edges, bufA, bufB, (float4*)acc,
                                     (const float4*)user_emb, (const float4*)item_emb, 1, 0);
  k_agg<<<gridAgg, 256, 0, stream>>>(row_ptr, edges, bufB, bufA, (float4*)acc,
                                     (const float4*)user_emb, (const float4*)item_emb, 0, 0);
  k_agg<<<gridAgg, 256, 0, stream>>>(row_ptr, edges, bufA, bufB, (float4*)acc,
                                     (const float4*)user_emb, (const float4*)item_emb, 0, 1);

  k_kl<<<640, 256, 0, stream>>>(acc, lin_w, lin_b, accums);
  k_batch_user<<<BB / 4, 256, 0, stream>>>(acc, user_emb, eps, user_int, lin_w, lin_b,
                                           users, pos_items, neg_items,
                                           ugen, uio, ugen_b, uio_b, accums);
  k_batch_item<<<BB / 4, 256, 0, stream>>>(acc, item_emb, eps, item_int, lin_w, lin_b,
                                           pos_items, neg_items,
                                           igen, iio, igen_b, iio_b, accums);
  k_nce_mfma<<<dim3(64, 8), 256, 0, stream>>>(ugen_b, uio_b, igen_b, iio_b, negu, negi);
  k_nce_final<<<(2 * BB) / 4, 256, 0, stream>>>(ugen, uio, igen, iio, negu, negi, accums);
  k_fin<<<1, 256, 0, stream>>>(user_int, item_int, accums, out);
}

// Round 2
// 559.605 us; speedup vs baseline: 1.0497x; 1.0023x over previous
//
#include <hip/hip_runtime.h>

#define NU 50000
#define NI 100000
#define NT 150000
#define BB 4096
#define NBUCK 147   // ceil(NT/1024)
#define BCAP 24576  // per-bucket edge capacity: mean 21504, sd ~143 -> +21 sigma
#define NCH 8       // chunks per bucket in CSR build

typedef __attribute__((ext_vector_type(8))) short bf16x8;
typedef __attribute__((ext_vector_type(4))) float f32x4;
typedef __attribute__((ext_vector_type(2))) float f32x2;
typedef unsigned long long u64;

__device__ __forceinline__ float softplusf(float x) {
  return fmaxf(x, 0.f) + log1pf(expf(-fabsf(x)));
}
__device__ __forceinline__ float wsum(float v) {
#pragma unroll
  for (int o = 32; o > 0; o >>= 1) v += __shfl_xor(v, o, 64);
  return v;
}
__device__ __forceinline__ float wmax(float v) {
#pragma unroll
  for (int o = 32; o > 0; o >>= 1) v = fmaxf(v, __shfl_xor(v, o, 64));
  return v;
}
__device__ __forceinline__ unsigned short f2b(float x) {
  unsigned u = __float_as_uint(x);
  return (unsigned short)((u + 0x7FFFu + ((u >> 16) & 1u)) >> 16);
}
__device__ __forceinline__ float b2f(unsigned us) {  // low 16 bits = bf16
  return __uint_as_float(us << 16);
}
__device__ __forceinline__ void unp4(u64 v, float* o) {
  unsigned lo = (unsigned)v, hi = (unsigned)(v >> 32);
  o[0] = __uint_as_float(lo << 16);
  o[1] = __uint_as_float(lo & 0xffff0000u);
  o[2] = __uint_as_float(hi << 16);
  o[3] = __uint_as_float(hi & 0xffff0000u);
}
__device__ __forceinline__ u64 pk4(float x0, float x1, float x2, float x3) {
  return (u64)((unsigned)f2b(x0) | ((unsigned)f2b(x1) << 16)) |
         ((u64)((unsigned)f2b(x2) | ((unsigned)f2b(x3) << 16)) << 32);
}

// ---------------- setup ----------------
// replaces 4 hipMemsetAsync dispatches
__global__ void k_zero(int* __restrict__ gcur, float* __restrict__ negu,
                       float* __restrict__ negi, double* __restrict__ accums,
                       unsigned* __restrict__ ticket) {
  int t = threadIdx.x;
  for (int i = t; i < NBUCK; i += 256) gcur[i] = 0;
  for (int i = t; i < BB; i += 256) { negu[i] = 0.f; negi[i] = 0.f; }
  if (t < 8) accums[t] = 0.0;
  if (t == 0) *ticket = 0;
}

// ---------------- CSR build ----------------
__global__ __launch_bounds__(256) void k_part(const int* __restrict__ h,
                                              const int* __restrict__ t,
                                              int* __restrict__ gcur,
                                              uint2* __restrict__ part, int E) {
  __shared__ int cnt[NBUCK];
  __shared__ int base[NBUCK];
  for (int b = threadIdx.x; b < NBUCK; b += 256) cnt[b] = 0;
  __syncthreads();
  int e0 = blockIdx.x * 4096 + threadIdx.x * 16;
  int nval = E - e0;
  nval = nval < 0 ? 0 : (nval > 16 ? 16 : nval);
  int hh[16], tt[16];
  if (nval == 16) {
    const int4* hp = (const int4*)(h + e0);
    const int4* tp = (const int4*)(t + e0);
#pragma unroll
    for (int j = 0; j < 4; j++) {
      int4 v = hp[j];
      hh[j * 4] = v.x; hh[j * 4 + 1] = v.y; hh[j * 4 + 2] = v.z; hh[j * 4 + 3] = v.w;
      int4 w = tp[j];
      tt[j * 4] = w.x; tt[j * 4 + 1] = w.y; tt[j * 4 + 2] = w.z; tt[j * 4 + 3] = w.w;
    }
  } else {
    for (int j = 0; j < nval; j++) { hh[j] = h[e0 + j]; tt[j] = t[e0 + j]; }
  }
  for (int j = 0; j < nval; j++) atomicAdd(&cnt[hh[j] >> 10], 1);
  __syncthreads();
  for (int b = threadIdx.x; b < NBUCK; b += 256) {
    int c = cnt[b];
    base[b] = c ? atomicAdd(&gcur[b], c) : 0;
    cnt[b] = 0;
  }
  __syncthreads();
  for (int j = 0; j < nval; j++) {
    int b = hh[j] >> 10;
    int r = atomicAdd(&cnt[b], 1);
    uint2 v; v.x = (unsigned)hh[j]; v.y = (unsigned)tt[j];
    part[(size_t)b * BCAP + base[b] + r] = v;
  }
}

// cnt_chunk layout: [(b<<10)+n][c] (node-major, chunk-minor)
__global__ __launch_bounds__(256) void k_count2(const uint2* __restrict__ part,
                                                const int* __restrict__ gcur,
                                                int* __restrict__ cnt_chunk) {
  __shared__ int hist[1024];
  int b = blockIdx.x, c = blockIdx.y, tid = threadIdx.x;
  for (int i = tid; i < 1024; i += 256) hist[i] = 0;
  __syncthreads();
  int m = gcur[b];
  int lo = (int)(((long long)m * c) >> 3);
  int hi = (int)(((long long)m * (c + 1)) >> 3);
  const uint2* pp = part + (size_t)b * BCAP;
  for (int i = lo + tid; i < hi; i += 256) atomicAdd(&hist[pp[i].x & 1023], 1);
  __syncthreads();
  for (int i = tid; i < 1024; i += 256)
    cnt_chunk[((((size_t)b << 10) + i) << 3) + c] = hist[i];
}

__global__ __launch_bounds__(256) void k_node(int* __restrict__ cnt_chunk,
                                              int* __restrict__ rloc_g,
                                              float* __restrict__ d_inv,
                                              int* __restrict__ btot) {
  __shared__ int sd[256];
  int b = blockIdx.x, tid = threadIdx.x;
  int n0 = b << 10;
  int pd[4];
  int s = 0;
#pragma unroll
  for (int j = 0; j < 4; j++) {
    int idx = tid * 4 + j;
    size_t base = ((size_t)(n0 + idx)) << 3;
    int run = 0;
#pragma unroll
    for (int c = 0; c < NCH; c++) {
      int v = cnt_chunk[base + c];
      cnt_chunk[base + c] = run;
      run += v;
    }
    int n = n0 + idx;
    if (n < NT) {
      d_inv[n] = 1.0f / sqrtf((float)run);  // deg >= 1 (self-loop)
      pd[j] = run;
    } else pd[j] = 0;
    s += pd[j];
  }
  sd[tid] = s;
  __syncthreads();
  for (int o = 1; o < 256; o <<= 1) {
    int x = (tid >= o) ? sd[tid - o] : 0;
    __syncthreads();
    sd[tid] += x;
    __syncthreads();
  }
  int run2 = sd[tid] - s;
#pragma unroll
  for (int j = 0; j < 4; j++) {
    int idx = tid * 4 + j, n = n0 + idx;
    if (n < NT) rloc_g[n] = run2;
    run2 += pd[j];
  }
  if (tid == 255) btot[b] = sd[255];
}

// k_rowptr folded in: every block redoes the cheap 147-entry scan of btot,
// c==0 blocks write row_ptr for their bucket (kills one dispatch).
__global__ __launch_bounds__(256) void k_fill2(const uint2* __restrict__ part,
                                               const int* __restrict__ gcur,
                                               const int* __restrict__ chunkpre,
                                               const int* __restrict__ rloc_g,
                                               const int* __restrict__ btot,
                                               const float* __restrict__ d_inv,
                                               uint2* __restrict__ edges,
                                               int* __restrict__ row_ptr) {
  __shared__ int curs[1024];
  __shared__ float dl[1024];
  __shared__ int sd[256];
  __shared__ int exs[256];
  int b = blockIdx.x, c = blockIdx.y, tid = threadIdx.x;
  int v = (tid < NBUCK) ? btot[tid] : 0;
  sd[tid] = v;
  __syncthreads();
  for (int o = 1; o < 256; o <<= 1) {
    int x = (tid >= o) ? sd[tid - o] : 0;
    __syncthreads();
    sd[tid] += x;
    __syncthreads();
  }
  exs[tid] = sd[tid] - v;  // for tid >= NBUCK this equals the grand total
  __syncthreads();
  int exB = exs[b];
  int n0 = b << 10;
  for (int i = tid; i < 1024; i += 256) {
    int n = n0 + i;
    if (n < NT) {
      int rp = exB + rloc_g[n];
      curs[i] = rp + chunkpre[((((size_t)b << 10) + i) << 3) + c];
      dl[i] = d_inv[n];
      if (c == 0) row_ptr[n] = rp;
    }
  }
  if (c == 0 && b == 0 && tid == 0) row_ptr[NT] = exs[255];
  __syncthreads();
  int m = gcur[b];
  int lo = (int)(((long long)m * c) >> 3);
  int hi = (int)(((long long)m * (c + 1)) >> 3);
  const uint2* pp = part + (size_t)b * BCAP;
  for (int i = lo + tid; i < hi; i += 256) {
    uint2 pe = pp[i];
    int slot = atomicAdd(&curs[pe.x & 1023], 1);
    float g = dl[pe.x & 1023] * d_inv[pe.y];
    uint2 w; w.x = pe.y; w.y = __float_as_uint(g);
    edges[slot] = w;
  }
}

// ---------------- propagation ----------------
// cur/nxt rows: 64 fp8(e4m3) dims packed as 16 dwords -> 64B row, ONE line
// per edge, FOUR rows per wave64 dword-gather.
// k_init also seeds acc (bf16 rows, 128B) = bf16(ego), so k_agg is a pure
// RMW in all passes (no first/ego path, pass1 reads 19MB not 38MB).
__global__ void k_init(const float4* __restrict__ ue, const float4* __restrict__ ie,
                       unsigned* __restrict__ cur, u64* __restrict__ acc64,
                       int nU4, int nTot4) {
  int i = blockIdx.x * 256 + threadIdx.x;
  if (i >= nTot4) return;
  float4 v = (i < nU4) ? ue[i] : ie[i - nU4];
  int p = __builtin_amdgcn_cvt_pk_fp8_f32(v.x, v.y, 0, false);
  p = __builtin_amdgcn_cvt_pk_fp8_f32(v.z, v.w, p, true);
  cur[i] = (unsigned)p;  // normal store: want bufA resident in L2 for pass 1
  __builtin_nontemporal_store(pk4(v.x, v.y, v.z, v.w), acc64 + i);
}

// wave = 4 quarter-groups; lane = (g = edge-group 0..3, d = dword 0..15).
// 32 edges/iter (2 rec loads + 8 gathers in flight) -> ~99% of nodes are one
// serial chain. acc is bf16 RMW (half the f32 traffic). Streams (edges, acc)
// are non-temporal so L2 keeps more of the 9.6MB gather working set.
// NOTE: flat named registers only — register ARRAYS here spill (round 7).
__global__ __launch_bounds__(256) void k_agg(const int* __restrict__ row_ptr,
                                             const uint2* __restrict__ edges,
                                             const unsigned* __restrict__ cur,
                                             unsigned* __restrict__ nxt,
                                             u64* __restrict__ acc64,
                                             int last) {
  int node = (blockIdx.x << 2) + (threadIdx.x >> 6);
  unsigned lane = threadIdx.x & 63;
  unsigned d = lane & 15;
  unsigned g = lane >> 4;
  int b4 = (int)(g << 2);
  int s = row_ptr[node], e = row_ptr[node + 1];
  float a0 = 0.f, a1 = 0.f, a2 = 0.f, a3 = 0.f;
  const u64* ep = (const u64*)edges;
  for (int i = s; i < e; i += 32) {
    int ia = i + (int)d;
    int ib = ia + 16;
    u64 ra = __builtin_nontemporal_load(ep + (ia < e ? ia : e - 1));
    u64 rb = __builtin_nontemporal_load(ep + (ib < e ? ib : e - 1));
    unsigned rax = (unsigned)ra;
    unsigned ray = (ia < e) ? (unsigned)(ra >> 32) : 0u;
    unsigned rbx = (unsigned)rb;
    unsigned rby = (ib < e) ? (unsigned)(rb >> 32) : 0u;
    unsigned iA0 = __shfl(rax, b4 + 0, 64); float gA0 = __uint_as_float(__shfl(ray, b4 + 0, 64));
    unsigned iA1 = __shfl(rax, b4 + 1, 64); float gA1 = __uint_as_float(__shfl(ray, b4 + 1, 64));
    unsigned iA2 = __shfl(rax, b4 + 2, 64); float gA2 = __uint_as_float(__shfl(ray, b4 + 2, 64));
    unsigned iA3 = __shfl(rax, b4 + 3, 64); float gA3 = __uint_as_float(__shfl(ray, b4 + 3, 64));
    unsigned vA0 = cur[(iA0 << 4) + d];
    unsigned vA1 = cur[(iA1 << 4) + d];
    unsigned vA2 = cur[(iA2 << 4) + d];
    unsigned vA3 = cur[(iA3 << 4) + d];
    unsigned iB0 = __shfl(rbx, b4 + 0, 64); float gB0 = __uint_as_float(__shfl(rby, b4 + 0, 64));
    unsigned iB1 = __shfl(rbx, b4 + 1, 64); float gB1 = __uint_as_float(__shfl(rby, b4 + 1, 64));
    unsigned iB2 = __shfl(rbx, b4 + 2, 64); float gB2 = __uint_as_float(__shfl(rby, b4 + 2, 64));
    unsigned iB3 = __shfl(rbx, b4 + 3, 64); float gB3 = __uint_as_float(__shfl(rby, b4 + 3, 64));
    unsigned vB0 = cur[(iB0 << 4) + d];
    unsigned vB1 = cur[(iB1 << 4) + d];
    unsigned vB2 = cur[(iB2 << 4) + d];
    unsigned vB3 = cur[(iB3 << 4) + d];
    f32x2 lo, hi;
    lo = __builtin_amdgcn_cvt_pk_f32_fp8(vA0, false);
    hi = __builtin_amdgcn_cvt_pk_f32_fp8(vA0, true);
    a0 = fmaf(gA0, lo.x, a0); a1 = fmaf(gA0, lo.y, a1);
    a2 = fmaf(gA0, hi.x, a2); a3 = fmaf(gA0, hi.y, a3);
    lo = __builtin_amdgcn_cvt_pk_f32_fp8(vA1, false);
    hi = __builtin_amdgcn_cvt_pk_f32_fp8(vA1, true);
    a0 = fmaf(gA1, lo.x, a0); a1 = fmaf(gA1, lo.y, a1);
    a2 = fmaf(gA1, hi.x, a2); a3 = fmaf(gA1, hi.y, a3);
    lo = __builtin_amdgcn_cvt_pk_f32_fp8(vA2, false);
    hi = __builtin_amdgcn_cvt_pk_f32_fp8(vA2, true);
    a0 = fmaf(gA2, lo.x, a0); a1 = fmaf(gA2, lo.y, a1);
    a2 = fmaf(gA2, hi.x, a2); a3 = fmaf(gA2, hi.y, a3);
    lo = __builtin_amdgcn_cvt_pk_f32_fp8(vA3, false);
    hi = __builtin_amdgcn_cvt_pk_f32_fp8(vA3, true);
    a0 = fmaf(gA3, lo.x, a0); a1 = fmaf(gA3, lo.y, a1);
    a2 = fmaf(gA3, hi.x, a2); a3 = fmaf(gA3, hi.y, a3);
    lo = __builtin_amdgcn_cvt_pk_f32_fp8(vB0, false);
    hi = __builtin_amdgcn_cvt_pk_f32_fp8(vB0, true);
    a0 = fmaf(gB0, lo.x, a0); a1 = fmaf(gB0, lo.y, a1);
    a2 = fmaf(gB0, hi.x, a2); a3 = fmaf(gB0, hi.y, a3);
    lo = __builtin_amdgcn_cvt_pk_f32_fp8(vB1, false);
    hi = __builtin_amdgcn_cvt_pk_f32_fp8(vB1, true);
    a0 = fmaf(gB1, lo.x, a0); a1 = fmaf(gB1, lo.y, a1);
    a2 = fmaf(gB1, hi.x, a2); a3 = fmaf(gB1, hi.y, a3);
    lo = __builtin_amdgcn_cvt_pk_f32_fp8(vB2, false);
    hi = __builtin_amdgcn_cvt_pk_f32_fp8(vB2, true);
    a0 = fmaf(gB2, lo.x, a0); a1 = fmaf(gB2, lo.y, a1);
    a2 = fmaf(gB2, hi.x, a2); a3 = fmaf(gB2, hi.y, a3);
    lo = __builtin_amdgcn_cvt_pk_f32_fp8(vB3, false);
    hi = __builtin_amdgcn_cvt_pk_f32_fp8(vB3, true);
    a0 = fmaf(gB3, lo.x, a0); a1 = fmaf(gB3, lo.y, a1);
    a2 = fmaf(gB3, hi.x, a2); a3 = fmaf(gB3, hi.y, a3);
  }
  a0 += __shfl_xor(a0, 16, 64);
  a1 += __shfl_xor(a1, 16, 64);
  a2 += __shfl_xor(a2, 16, 64);
  a3 += __shfl_xor(a3, 16, 64);
  a0 += __shfl_xor(a0, 32, 64);
  a1 += __shfl_xor(a1, 32, 64);
  a2 += __shfl_xor(a2, 32, 64);
  a3 += __shfl_xor(a3, 32, 64);
  unsigned ro = ((unsigned)node << 4) + d;
  if (g == 0) {
    u64 pv = __builtin_nontemporal_load(acc64 + ro);
    unsigned lo32 = (unsigned)pv, hi32 = (unsigned)(pv >> 32);
    float x0 = __uint_as_float(lo32 << 16) + a0;
    float x1 = __uint_as_float(lo32 & 0xffff0000u) + a1;
    float x2 = __uint_as_float(hi32 << 16) + a2;
    float x3 = __uint_as_float(hi32 & 0xffff0000u) + a3;
    __builtin_nontemporal_store(pk4(x0, x1, x2, x3), acc64 + ro);
  } else if (g == 1 && !last) {
    int p = __builtin_amdgcn_cvt_pk_fp8_f32(a0, a1, 0, false);
    p = __builtin_amdgcn_cvt_pk_fp8_f32(a2, a3, p, true);
    nxt[ro] = (unsigned)p;  // normal store: next pass gathers from it
  }
}

// ---------------- fused post pass: batch_user | batch_item | KL | int_loss ----------------
__global__ __launch_bounds__(256) void k_post(
    const unsigned short* __restrict__ accB,
    const float* __restrict__ user_emb, const float* __restrict__ item_emb,
    const float* __restrict__ eps,
    const float* __restrict__ user_int, const float* __restrict__ item_int,
    const float* __restrict__ lin_w, const float* __restrict__ lin_b,
    const int* __restrict__ users, const int* __restrict__ pos_items,
    const int* __restrict__ neg_items,
    unsigned short* __restrict__ ugen_b, unsigned short* __restrict__ uio_b,
    unsigned short* __restrict__ igen_b, unsigned short* __restrict__ iio_b,
    float* __restrict__ posu, float* __restrict__ posi,
    double* __restrict__ accums) {
  __shared__ float ui[64 * 130];
  __shared__ float lw[64 * 33];
  __shared__ float lb[64];
  __shared__ double red[8];
  int bid = blockIdx.x;
  int lane = threadIdx.x & 63;
  int wid = threadIdx.x >> 6;
  if (bid < 2048) {
    // ---- batch branch (user: bid<1024, item: bid>=1024) ----
    int isI = bid >> 10;
    int bb = bid & 1023;
    const float* intent = isI ? item_int : user_int;
    for (int i = threadIdx.x; i < 64 * 128; i += 256) ui[(i >> 7) * 130 + (i & 127)] = intent[i];
    for (int i = threadIdx.x; i < 64 * 32; i += 256) lw[(i >> 5) * 33 + (i & 31)] = lin_w[i];
    if (threadIdx.x < 64) lb[threadIdx.x] = lin_b[threadIdx.x];
    __syncthreads();
    int b = (bb << 2) + wid;
    int pi = pos_items[b], ni = neg_items[b];
    int u = isI ? 0 : users[b];
    int row = isI ? (NU + pi) : u;
    float m = b2f(accB[(size_t)row * 64 + lane]);
    int k0 = lane * 2;
    float l0 = 0.f, l1 = 0.f;
    for (int dd = 0; dd < 64; dd++) {
      float md = __shfl(m, dd, 64);
      l0 = fmaf(md, ui[dd * 130 + k0], l0);
      l1 = fmaf(md, ui[dd * 130 + k0 + 1], l1);
    }
    float mx = wmax(fmaxf(l0, l1));
    float p0 = expf(l0 - mx), p1 = expf(l1 - mx);
    float tot = wsum(p0 + p1);
    p0 /= tot; p1 /= tot;
    float sI = 0.f;
    for (int k = 0; k < 128; k++) {
      float pk = __shfl((k & 1) ? p1 : p0, k >> 1, 64);
      sI = fmaf(pk, ui[lane * 130 + k], sI);
    }
    float nrm = sqrtf(wsum(sI * sI));
    float io = sI / nrm;
    (isI ? iio_b : uio_b)[b * 64 + lane] = f2b(io);
    float sp = softplusf(m);
    float sdv = lb[lane] + 1e-8f;
#pragma unroll
    for (int j = 0; j < 32; j++) sdv = fmaf(__shfl(sp, j, 64), lw[lane * 33 + j], sdv);
    float ge = m + eps[(size_t)row * 64 + lane] * sdv;
    float gn = sqrtf(wsum(ge * ge));
    float go = ge / gn;
    (isI ? igen_b : ugen_b)[b * 64 + lane] = f2b(go);
    float pd = wsum(go * io);  // InfoNCE positive dot, fused here
    if (lane == 0) (isI ? posi : posu)[b] = pd;
    if (!isI) {
      float pv = b2f(accB[(size_t)(NU + pi) * 64 + lane]);
      float nv = b2f(accB[(size_t)(NU + ni) * 64 + lane]);
      float ps = wsum(m * pv);
      float ns = wsum(m * nv);
      float bpr = softplusf(ns - ps);
      float ue = user_emb[(size_t)u * 64 + lane];
      float es = wsum(ue * ue);
      if (lane == 0) { red[wid] = (double)bpr; red[4 + wid] = (double)es; }
      __syncthreads();
      if (threadIdx.x == 0) {
        atomicAdd(&accums[0], red[0] + red[1] + red[2] + red[3]);
        atomicAdd(&accums[2], red[4] + red[5] + red[6] + red[7]);
      }
    } else {
      float e0 = item_emb[(size_t)pi * 64 + lane];
      float e1 = item_emb[(size_t)ni * 64 + lane];
      float es = wsum(e0 * e0 + e1 * e1);
      if (lane == 0) red[wid] = (double)es;
      __syncthreads();
      if (threadIdx.x == 0) atomicAdd(&accums[2], red[0] + red[1] + red[2] + red[3]);
    }
  } else if (bid < 2048 + 640) {
    // ---- KL branch (MFMA over bf16 acc) ----
    int n = lane & 15, q = lane >> 4;
    bf16x8 B0, B1, B2, B3;
    float lb0, lb1, lb2, lb3;
    {
      const float* w0 = lin_w + (0 * 16 + n) * 32 + q * 8;
      const float* w1 = lin_w + (1 * 16 + n) * 32 + q * 8;
      const float* w2 = lin_w + (2 * 16 + n) * 32 + q * 8;
      const float* w3 = lin_w + (3 * 16 + n) * 32 + q * 8;
#pragma unroll
      for (int j = 0; j < 8; j++) {
        B0[j] = (short)f2b(w0[j]);
        B1[j] = (short)f2b(w1[j]);
        B2[j] = (short)f2b(w2[j]);
        B3[j] = (short)f2b(w3[j]);
      }
      lb0 = lin_b[0 * 16 + n] + 1e-8f;
      lb1 = lin_b[1 * 16 + n] + 1e-8f;
      lb2 = lin_b[2 * 16 + n] + 1e-8f;
      lb3 = lin_b[3 * 16 + n] + 1e-8f;
    }
    const int TI = NT / 16;
    int w0id = (bid - 2048) * 4 + wid;
    int nwv = 640 * 4;
    double dsum = 0.0;
    for (int tile = w0id; tile < TI; tile += nwv) {
      const u64* rp = (const u64*)(accB + (size_t)(tile * 16 + n) * 64 + q * 8);
      u64 A0 = __builtin_nontemporal_load(rp);
      u64 A1 = __builtin_nontemporal_load(rp + 1);
      u64 C0 = __builtin_nontemporal_load(rp + 8);   // +32 dims
      u64 C1 = __builtin_nontemporal_load(rp + 9);
      float av[8], bv[8];
      unp4(A0, av); unp4(A1, av + 4);
      unp4(C0, bv); unp4(C1, bv + 4);
      float msum = 0.f;
#pragma unroll
      for (int j = 0; j < 8; j++) msum += av[j] * av[j] + bv[j] * bv[j];
      bf16x8 Af;
#pragma unroll
      for (int j = 0; j < 8; j++) Af[j] = (short)f2b(softplusf(av[j]));
      f32x4 z = {0.f, 0.f, 0.f, 0.f};
      f32x4 c0 = __builtin_amdgcn_mfma_f32_16x16x32_bf16(Af, B0, z, 0, 0, 0);
      f32x4 c1 = __builtin_amdgcn_mfma_f32_16x16x32_bf16(Af, B1, z, 0, 0, 0);
      f32x4 c2 = __builtin_amdgcn_mfma_f32_16x16x32_bf16(Af, B2, z, 0, 0, 0);
      f32x4 c3 = __builtin_amdgcn_mfma_f32_16x16x32_bf16(Af, B3, z, 0, 0, 0);
      float ksum = 0.f;
#pragma unroll
      for (int r = 0; r < 4; r++) {
        float s0 = c0[r] + lb0, s1 = c1[r] + lb1, s2 = c2[r] + lb2, s3 = c3[r] + lb3;
        ksum += -0.5f * (1.f + 2.f * s0 - __expf(2.f * s0));
        ksum += -0.5f * (1.f + 2.f * s1 - __expf(2.f * s1));
        ksum += -0.5f * (1.f + 2.f * s2 - __expf(2.f * s2));
        ksum += -0.5f * (1.f + 2.f * s3 - __expf(2.f * s3));
      }
      dsum += (double)wsum(ksum + 0.5f * msum);
    }
    if (lane == 0) red[wid] = dsum;
    __syncthreads();
    if (threadIdx.x == 0)
      atomicAdd(&accums[1], red[0] + red[1] + red[2] + red[3]);
  } else {
    // ---- int_loss block (reads inputs only) ----
    float s = 0.f;
    for (int i = threadIdx.x; i < 64 * 128; i += 256) {
      float a = user_int[i], b = item_int[i];
      s = fmaf(a, a, s);
      s = fmaf(b, b, s);
    }
    s = wsum(s);
    if (lane == 0) red[wid] = (double)s;
    __syncthreads();
    if (threadIdx.x == 0) atomicAdd(&accums[3], red[0] + red[1] + red[2] + red[3]);
  }
}

// ---------------- InfoNCE negatives (bf16 MFMA) + ticketed final combine ----------------
__global__ __launch_bounds__(256) void k_nce(
    const unsigned short* __restrict__ e1u, const unsigned short* __restrict__ e2u,
    const unsigned short* __restrict__ e1i, const unsigned short* __restrict__ e2i,
    float* __restrict__ negu, float* __restrict__ negi,
    const float* __restrict__ posu, const float* __restrict__ posi,
    const double* __restrict__ accums, float* __restrict__ out,
    unsigned* __restrict__ ticket) {
  __shared__ bool fin;
  __shared__ double redd[4];
  {
    int pr = blockIdx.y >> 2, jq = blockIdx.y & 3;
    const unsigned short* e1 = pr ? e1i : e1u;
    const unsigned short* e2 = pr ? e2i : e2u;
    float* nego = pr ? negi : negu;
    int wid = threadIdx.x >> 6, lane = threadIdx.x & 63;
    int q = lane >> 4, n = lane & 15;
    int i0 = blockIdx.x * 64 + wid * 16;
    const bf16x8* arow = (const bf16x8*)(e1 + (size_t)(i0 + n) * 64 + q * 8);
    bf16x8 a0 = arow[0];
    bf16x8 a1 = arow[4];
    f32x4 accv = {0.f, 0.f, 0.f, 0.f};
    int j0 = jq * 1024;
    for (int jt = 0; jt < 64; jt++) {
      const bf16x8* brow = (const bf16x8*)(e2 + (size_t)(j0 + jt * 16 + n) * 64 + q * 8);
      bf16x8 b0 = brow[0];
      bf16x8 b1 = brow[4];
      f32x4 c = {0.f, 0.f, 0.f, 0.f};
      c = __builtin_amdgcn_mfma_f32_16x16x32_bf16(a0, b0, c, 0, 0, 0);
      c = __builtin_amdgcn_mfma_f32_16x16x32_bf16(a1, b1, c, 0, 0, 0);
#pragma unroll
      for (int r = 0; r < 4; r++) accv[r] += __expf(5.0f * c[r]);
    }
#pragma unroll
    for (int o = 1; o < 16; o <<= 1) {
#pragma unroll
      for (int r = 0; r < 4; r++) accv[r] += __shfl_xor(accv[r], o, 64);
    }
    if (n == 0) {
#pragma unroll
      for (int r = 0; r < 4; r++) atomicAdd(&nego[i0 + q * 4 + r], accv[r]);
    }
  }
  __threadfence();
  __syncthreads();
  if (threadIdx.x == 0) {
    unsigned old = atomicAdd(ticket, 1u);
    fin = (old == 64u * 8u - 1u);
  }
  __syncthreads();
  if (!fin) return;
  // last block: nce log-sum + final combine (replaces k_nce_final + k_fin).
  // negu/negi were written by other blocks' atomics -> read back via atomic
  // (device-scope, bypasses any stale per-XCD cache).
  double cl = 0.0;
  for (int i = threadIdx.x; i < 2 * BB; i += 256) {
    int pr = i >> 12, idx = i & (BB - 1);
    float ng = atomicAdd(pr ? &negi[idx] : &negu[idx], 0.0f);
    float dt = pr ? posi[idx] : posu[idx];
    float pos = expf(5.0f * dt);
    cl += (double)(-logf(pos / (ng + 1e-8f) + 1e-8f));
  }
#pragma unroll
  for (int o = 32; o > 0; o >>= 1) cl += __shfl_xor(cl, o, 64);
  int lane = threadIdx.x & 63, wid = threadIdx.x >> 6;
  if (lane == 0) redd[wid] = cl;
  __syncthreads();
  if (threadIdx.x == 0) {
    double cls = redd[0] + redd[1] + redd[2] + redd[3];
    double bpr = accums[0] / (double)BB;
    double kl = 0.01 * accums[1] / (double)NT;
    out[0] = (float)(bpr + kl);
    out[1] = (float)(0.1 * cls / (double)BB);
    out[2] = (float)(1e-5 * accums[2]);
    out[3] = (float)(1e-5 * accums[3]);
  }
}

extern "C" void kernel_launch(void* const* d_in, const int* in_sizes, int n_in,
                              void* d_out, int out_size, void* d_ws, size_t ws_size,
                              hipStream_t stream) {
  const float* user_emb = (const float*)d_in[0];
  const float* item_emb = (const float*)d_in[1];
  const float* user_int = (const float*)d_in[2];
  const float* item_int = (const float*)d_in[3];
  const float* lin_w = (const float*)d_in[4];
  const float* lin_b = (const float*)d_in[5];
  const float* eps = (const float*)d_in[6];
  const int* h_list = (const int*)d_in[7];
  const int* t_list = (const int*)d_in[8];
  const int* users = (const int*)d_in[9];
  const int* pos_items = (const int*)d_in[10];
  const int* neg_items = (const int*)d_in[11];
  float* out = (float*)d_out;
  const int E = in_sizes[7];

  char* ws = (char*)d_ws;
  size_t off = 0;
  auto take = [&](size_t bytes) -> char* {
    char* p = ws + off;
    off = (off + bytes + 255) & ~(size_t)255;
    return p;
  };
  int* row_ptr = (int*)take((size_t)(NT + 1) * 4);
  float* d_inv = (float*)take((size_t)NT * 4);
  int* rloc_g = (int*)take((size_t)NT * 4);
  int* cnt_chunk = (int*)take((size_t)NBUCK * NCH * 1024 * 4);
  int* gcur = (int*)take(NBUCK * 4);
  int* btot = (int*)take(NBUCK * 4);
  uint2* edges = (uint2*)take((size_t)E * 8);
  unsigned* bufA = (unsigned*)take((size_t)NT * 16 * 4);  // fp8 rows (16 dwords)
  unsigned* bufB = (unsigned*)take((size_t)NT * 16 * 4);
  // accB (bf16 rows, 19.2MB) shares a region with part (28.9MB): part's last
  // read is k_fill2; accB is first written in k_init (which runs after).
  unsigned short* accB = (unsigned short*)take((size_t)NBUCK * BCAP * 8);
  unsigned short* ugen_b = (unsigned short*)take((size_t)BB * 64 * 2);
  unsigned short* igen_b = (unsigned short*)take((size_t)BB * 64 * 2);
  unsigned short* uio_b = (unsigned short*)take((size_t)BB * 64 * 2);
  unsigned short* iio_b = (unsigned short*)take((size_t)BB * 64 * 2);
  float* posu = (float*)take((size_t)BB * 4);
  float* posi = (float*)take((size_t)BB * 4);
  float* negu = (float*)take((size_t)BB * 4);
  float* negi = (float*)take((size_t)BB * 4);
  double* accums = (double*)take(64);
  unsigned* ticket = (unsigned*)take(4);
  if (off > ws_size) return;
  uint2* part = (uint2*)accB;
  u64* acc64 = (u64*)accB;

  k_zero<<<1, 256, 0, stream>>>(gcur, negu, negi, accums, ticket);

  int gridP = (E + 4095) / 4096;
  k_part<<<gridP, 256, 0, stream>>>(h_list, t_list, gcur, part, E);
  k_count2<<<dim3(NBUCK, NCH), 256, 0, stream>>>(part, gcur, cnt_chunk);
  k_node<<<NBUCK, 256, 0, stream>>>(cnt_chunk, rloc_g, d_inv, btot);
  k_fill2<<<dim3(NBUCK, NCH), 256, 0, stream>>>(part, gcur, cnt_chunk, rloc_g,
                                                btot, d_inv, edges, row_ptr);

  int nU4 = NU * 16, nTot4 = NT * 16;
  k_init<<<(nTot4 + 255) / 256, 256, 0, stream>>>((const float4*)user_emb,
                                                  (const float4*)item_emb, bufA,
                                                  acc64, nU4, nTot4);
  int gridAgg = NT / 4;
  k_agg<<<gridAgg, 256, 0, stream>>>(row_ptr, edges, bufA, bufB, acc64, 0);
  k_agg<<<gridAgg, 256, 0, stream>>>(row_ptr, edges, bufB, bufA, acc64, 0);
  k_agg<<<gridAgg, 256, 0, stream>>>(row_ptr, edges, bufA, bufB, acc64, 1);

  k_post<<<2048 + 640 + 1, 256, 0, stream>>>(accB, user_emb, item_emb, eps,
                                             user_int, item_int, lin_w, lin_b,
                                             users, pos_items, neg_items,
                                             ugen_b, uio_b, igen_b, iio_b,
                                             posu, posi, accums);
  k_nce<<<dim3(64, 8), 256, 0, stream>>>(ugen_b, uio_b, igen_b, iio_b,
                                         negu, negi, posu, posi, accums, out,
                                         ticket);
}

// Round 3
// 522.516 us; speedup vs baseline: 1.1242x; 1.0710x over previous
//
#include <hip/hip_runtime.h>

#define NU 50000
#define NI 100000
#define NT 150000
#define BB 4096
#define NBUCK 147   // ceil(NT/1024)
#define BCAP 24576  // per-bucket edge capacity: mean 21504, sd ~143 -> +21 sigma
#define NCH 8       // chunks per bucket in CSR build

typedef __attribute__((ext_vector_type(8))) short bf16x8;
typedef __attribute__((ext_vector_type(4))) float f32x4;
typedef __attribute__((ext_vector_type(2))) float f32x2;
typedef unsigned long long u64;

__device__ __forceinline__ float softplusf(float x) {
  // fast softplus: feeds bf16 (8-bit mantissa) -> __logf/__expf precision is
  // ~1e-6 rel, invisible downstream. log1pf was a libm call (~30 VALU ops).
  return fmaxf(x, 0.f) + __logf(1.f + __expf(-fabsf(x)));
}
__device__ __forceinline__ float wsum(float v) {
#pragma unroll
  for (int o = 32; o > 0; o >>= 1) v += __shfl_xor(v, o, 64);
  return v;
}
__device__ __forceinline__ float wmax(float v) {
#pragma unroll
  for (int o = 32; o > 0; o >>= 1) v = fmaxf(v, __shfl_xor(v, o, 64));
  return v;
}
__device__ __forceinline__ unsigned short f2b(float x) {
  unsigned u = __float_as_uint(x);
  return (unsigned short)((u + 0x7FFFu + ((u >> 16) & 1u)) >> 16);
}
__device__ __forceinline__ float b2f(unsigned us) {  // low 16 bits = bf16
  return __uint_as_float(us << 16);
}
__device__ __forceinline__ void unp4(u64 v, float* o) {
  unsigned lo = (unsigned)v, hi = (unsigned)(v >> 32);
  o[0] = __uint_as_float(lo << 16);
  o[1] = __uint_as_float(lo & 0xffff0000u);
  o[2] = __uint_as_float(hi << 16);
  o[3] = __uint_as_float(hi & 0xffff0000u);
}
__device__ __forceinline__ u64 pk4(float x0, float x1, float x2, float x3) {
  return (u64)((unsigned)f2b(x0) | ((unsigned)f2b(x1) << 16)) |
         ((u64)((unsigned)f2b(x2) | ((unsigned)f2b(x3) << 16)) << 32);
}

// ---------------- setup ----------------
__global__ void k_zero(int* __restrict__ gcur, float* __restrict__ negu,
                       float* __restrict__ negi, double* __restrict__ accums) {
  int t = threadIdx.x;
  for (int i = t; i < NBUCK; i += 256) gcur[i] = 0;
  for (int i = t; i < BB; i += 256) { negu[i] = 0.f; negi[i] = 0.f; }
  if (t < 8) accums[t] = 0.0;
}

// ---------------- CSR build ----------------
__global__ __launch_bounds__(256) void k_part(const int* __restrict__ h,
                                              const int* __restrict__ t,
                                              int* __restrict__ gcur,
                                              uint2* __restrict__ part, int E) {
  __shared__ int cnt[NBUCK];
  __shared__ int base[NBUCK];
  for (int b = threadIdx.x; b < NBUCK; b += 256) cnt[b] = 0;
  __syncthreads();
  int e0 = blockIdx.x * 4096 + threadIdx.x * 16;
  int nval = E - e0;
  nval = nval < 0 ? 0 : (nval > 16 ? 16 : nval);
  int hh[16], tt[16];
  if (nval == 16) {
    const int4* hp = (const int4*)(h + e0);
    const int4* tp = (const int4*)(t + e0);
#pragma unroll
    for (int j = 0; j < 4; j++) {
      int4 v = hp[j];
      hh[j * 4] = v.x; hh[j * 4 + 1] = v.y; hh[j * 4 + 2] = v.z; hh[j * 4 + 3] = v.w;
      int4 w = tp[j];
      tt[j * 4] = w.x; tt[j * 4 + 1] = w.y; tt[j * 4 + 2] = w.z; tt[j * 4 + 3] = w.w;
    }
  } else {
    for (int j = 0; j < nval; j++) { hh[j] = h[e0 + j]; tt[j] = t[e0 + j]; }
  }
  for (int j = 0; j < nval; j++) atomicAdd(&cnt[hh[j] >> 10], 1);
  __syncthreads();
  for (int b = threadIdx.x; b < NBUCK; b += 256) {
    int c = cnt[b];
    base[b] = c ? atomicAdd(&gcur[b], c) : 0;
    cnt[b] = 0;
  }
  __syncthreads();
  for (int j = 0; j < nval; j++) {
    int b = hh[j] >> 10;
    int r = atomicAdd(&cnt[b], 1);
    uint2 v; v.x = (unsigned)hh[j]; v.y = (unsigned)tt[j];
    part[(size_t)b * BCAP + base[b] + r] = v;
  }
}

// cnt_chunk layout: [(b<<10)+n][c] (node-major, chunk-minor)
__global__ __launch_bounds__(256) void k_count2(const uint2* __restrict__ part,
                                                const int* __restrict__ gcur,
                                                int* __restrict__ cnt_chunk) {
  __shared__ int hist[1024];
  int b = blockIdx.x, c = blockIdx.y, tid = threadIdx.x;
  for (int i = tid; i < 1024; i += 256) hist[i] = 0;
  __syncthreads();
  int m = gcur[b];
  int lo = (int)(((long long)m * c) >> 3);
  int hi = (int)(((long long)m * (c + 1)) >> 3);
  const uint2* pp = part + (size_t)b * BCAP;
  for (int i = lo + tid; i < hi; i += 256) atomicAdd(&hist[pp[i].x & 1023], 1);
  __syncthreads();
  for (int i = tid; i < 1024; i += 256)
    cnt_chunk[((((size_t)b << 10) + i) << 3) + c] = hist[i];
}

__global__ __launch_bounds__(256) void k_node(int* __restrict__ cnt_chunk,
                                              int* __restrict__ rloc_g,
                                              float* __restrict__ d_inv,
                                              int* __restrict__ btot) {
  __shared__ int sd[256];
  int b = blockIdx.x, tid = threadIdx.x;
  int n0 = b << 10;
  int pd[4];
  int s = 0;
#pragma unroll
  for (int j = 0; j < 4; j++) {
    int idx = tid * 4 + j;
    size_t base = ((size_t)(n0 + idx)) << 3;
    int run = 0;
#pragma unroll
    for (int c = 0; c < NCH; c++) {
      int v = cnt_chunk[base + c];
      cnt_chunk[base + c] = run;
      run += v;
    }
    int n = n0 + idx;
    if (n < NT) {
      d_inv[n] = 1.0f / sqrtf((float)run);  // deg >= 1 (self-loop)
      pd[j] = run;
    } else pd[j] = 0;
    s += pd[j];
  }
  sd[tid] = s;
  __syncthreads();
  for (int o = 1; o < 256; o <<= 1) {
    int x = (tid >= o) ? sd[tid - o] : 0;
    __syncthreads();
    sd[tid] += x;
    __syncthreads();
  }
  int run2 = sd[tid] - s;
#pragma unroll
  for (int j = 0; j < 4; j++) {
    int idx = tid * 4 + j, n = n0 + idx;
    if (n < NT) rloc_g[n] = run2;
    run2 += pd[j];
  }
  if (tid == 255) btot[b] = sd[255];
}

// k_rowptr folded in: every block redoes the cheap 147-entry scan of btot,
// c==0 blocks write row_ptr for their bucket.
__global__ __launch_bounds__(256) void k_fill2(const uint2* __restrict__ part,
                                               const int* __restrict__ gcur,
                                               const int* __restrict__ chunkpre,
                                               const int* __restrict__ rloc_g,
                                               const int* __restrict__ btot,
                                               const float* __restrict__ d_inv,
                                               uint2* __restrict__ edges,
                                               int* __restrict__ row_ptr) {
  __shared__ int curs[1024];
  __shared__ float dl[1024];
  __shared__ int sd[256];
  __shared__ int exs[256];
  int b = blockIdx.x, c = blockIdx.y, tid = threadIdx.x;
  int v = (tid < NBUCK) ? btot[tid] : 0;
  sd[tid] = v;
  __syncthreads();
  for (int o = 1; o < 256; o <<= 1) {
    int x = (tid >= o) ? sd[tid - o] : 0;
    __syncthreads();
    sd[tid] += x;
    __syncthreads();
  }
  exs[tid] = sd[tid] - v;
  __syncthreads();
  int exB = exs[b];
  int n0 = b << 10;
  for (int i = tid; i < 1024; i += 256) {
    int n = n0 + i;
    if (n < NT) {
      int rp = exB + rloc_g[n];
      curs[i] = rp + chunkpre[((((size_t)b << 10) + i) << 3) + c];
      dl[i] = d_inv[n];
      if (c == 0) row_ptr[n] = rp;
    }
  }
  if (c == 0 && b == 0 && tid == 0) row_ptr[NT] = exs[255];
  __syncthreads();
  int m = gcur[b];
  int lo = (int)(((long long)m * c) >> 3);
  int hi = (int)(((long long)m * (c + 1)) >> 3);
  const uint2* pp = part + (size_t)b * BCAP;
  for (int i = lo + tid; i < hi; i += 256) {
    uint2 pe = pp[i];
    int slot = atomicAdd(&curs[pe.x & 1023], 1);
    float g = dl[pe.x & 1023] * d_inv[pe.y];
    uint2 w; w.x = pe.y; w.y = __float_as_uint(g);
    edges[slot] = w;
  }
}

// ---------------- propagation ----------------
__global__ void k_init(const float4* __restrict__ ue, const float4* __restrict__ ie,
                       unsigned* __restrict__ cur, u64* __restrict__ acc64,
                       int nU4, int nTot4) {
  int i = blockIdx.x * 256 + threadIdx.x;
  if (i >= nTot4) return;
  float4 v = (i < nU4) ? ue[i] : ie[i - nU4];
  int p = __builtin_amdgcn_cvt_pk_fp8_f32(v.x, v.y, 0, false);
  p = __builtin_amdgcn_cvt_pk_fp8_f32(v.z, v.w, p, true);
  cur[i] = (unsigned)p;
  __builtin_nontemporal_store(pk4(v.x, v.y, v.z, v.w), acc64 + i);
}

// wave = 4 quarter-groups; lane = (g = edge-group 0..3, d = dword 0..15).
// 32 edges/iter (2 rec loads + 8 gathers in flight). acc is bf16 RMW.
// NOTE: flat named registers only — register ARRAYS here spill (round 7).
__global__ __launch_bounds__(256) void k_agg(const int* __restrict__ row_ptr,
                                             const uint2* __restrict__ edges,
                                             const unsigned* __restrict__ cur,
                                             unsigned* __restrict__ nxt,
                                             u64* __restrict__ acc64,
                                             int last) {
  int node = (blockIdx.x << 2) + (threadIdx.x >> 6);
  unsigned lane = threadIdx.x & 63;
  unsigned d = lane & 15;
  unsigned g = lane >> 4;
  int b4 = (int)(g << 2);
  int s = row_ptr[node], e = row_ptr[node + 1];
  float a0 = 0.f, a1 = 0.f, a2 = 0.f, a3 = 0.f;
  const u64* ep = (const u64*)edges;
  for (int i = s; i < e; i += 32) {
    int ia = i + (int)d;
    int ib = ia + 16;
    u64 ra = __builtin_nontemporal_load(ep + (ia < e ? ia : e - 1));
    u64 rb = __builtin_nontemporal_load(ep + (ib < e ? ib : e - 1));
    unsigned rax = (unsigned)ra;
    unsigned ray = (ia < e) ? (unsigned)(ra >> 32) : 0u;
    unsigned rbx = (unsigned)rb;
    unsigned rby = (ib < e) ? (unsigned)(rb >> 32) : 0u;
    unsigned iA0 = __shfl(rax, b4 + 0, 64); float gA0 = __uint_as_float(__shfl(ray, b4 + 0, 64));
    unsigned iA1 = __shfl(rax, b4 + 1, 64); float gA1 = __uint_as_float(__shfl(ray, b4 + 1, 64));
    unsigned iA2 = __shfl(rax, b4 + 2, 64); float gA2 = __uint_as_float(__shfl(ray, b4 + 2, 64));
    unsigned iA3 = __shfl(rax, b4 + 3, 64); float gA3 = __uint_as_float(__shfl(ray, b4 + 3, 64));
    unsigned vA0 = cur[(iA0 << 4) + d];
    unsigned vA1 = cur[(iA1 << 4) + d];
    unsigned vA2 = cur[(iA2 << 4) + d];
    unsigned vA3 = cur[(iA3 << 4) + d];
    unsigned iB0 = __shfl(rbx, b4 + 0, 64); float gB0 = __uint_as_float(__shfl(rby, b4 + 0, 64));
    unsigned iB1 = __shfl(rbx, b4 + 1, 64); float gB1 = __uint_as_float(__shfl(rby, b4 + 1, 64));
    unsigned iB2 = __shfl(rbx, b4 + 2, 64); float gB2 = __uint_as_float(__shfl(rby, b4 + 2, 64));
    unsigned iB3 = __shfl(rbx, b4 + 3, 64); float gB3 = __uint_as_float(__shfl(rby, b4 + 3, 64));
    unsigned vB0 = cur[(iB0 << 4) + d];
    unsigned vB1 = cur[(iB1 << 4) + d];
    unsigned vB2 = cur[(iB2 << 4) + d];
    unsigned vB3 = cur[(iB3 << 4) + d];
    f32x2 lo, hi;
    lo = __builtin_amdgcn_cvt_pk_f32_fp8(vA0, false);
    hi = __builtin_amdgcn_cvt_pk_f32_fp8(vA0, true);
    a0 = fmaf(gA0, lo.x, a0); a1 = fmaf(gA0, lo.y, a1);
    a2 = fmaf(gA0, hi.x, a2); a3 = fmaf(gA0, hi.y, a3);
    lo = __builtin_amdgcn_cvt_pk_f32_fp8(vA1, false);
    hi = __builtin_amdgcn_cvt_pk_f32_fp8(vA1, true);
    a0 = fmaf(gA1, lo.x, a0); a1 = fmaf(gA1, lo.y, a1);
    a2 = fmaf(gA1, hi.x, a2); a3 = fmaf(gA1, hi.y, a3);
    lo = __builtin_amdgcn_cvt_pk_f32_fp8(vA2, false);
    hi = __builtin_amdgcn_cvt_pk_f32_fp8(vA2, true);
    a0 = fmaf(gA2, lo.x, a0); a1 = fmaf(gA2, lo.y, a1);
    a2 = fmaf(gA2, hi.x, a2); a3 = fmaf(gA2, hi.y, a3);
    lo = __builtin_amdgcn_cvt_pk_f32_fp8(vA3, false);
    hi = __builtin_amdgcn_cvt_pk_f32_fp8(vA3, true);
    a0 = fmaf(gA3, lo.x, a0); a1 = fmaf(gA3, lo.y, a1);
    a2 = fmaf(gA3, hi.x, a2); a3 = fmaf(gA3, hi.y, a3);
    lo = __builtin_amdgcn_cvt_pk_f32_fp8(vB0, false);
    hi = __builtin_amdgcn_cvt_pk_f32_fp8(vB0, true);
    a0 = fmaf(gB0, lo.x, a0); a1 = fmaf(gB0, lo.y, a1);
    a2 = fmaf(gB0, hi.x, a2); a3 = fmaf(gB0, hi.y, a3);
    lo = __builtin_amdgcn_cvt_pk_f32_fp8(vB1, false);
    hi = __builtin_amdgcn_cvt_pk_f32_fp8(vB1, true);
    a0 = fmaf(gB1, lo.x, a0); a1 = fmaf(gB1, lo.y, a1);
    a2 = fmaf(gB1, hi.x, a2); a3 = fmaf(gB1, hi.y, a3);
    lo = __builtin_amdgcn_cvt_pk_f32_fp8(vB2, false);
    hi = __builtin_amdgcn_cvt_pk_f32_fp8(vB2, true);
    a0 = fmaf(gB2, lo.x, a0); a1 = fmaf(gB2, lo.y, a1);
    a2 = fmaf(gB2, hi.x, a2); a3 = fmaf(gB2, hi.y, a3);
    lo = __builtin_amdgcn_cvt_pk_f32_fp8(vB3, false);
    hi = __builtin_amdgcn_cvt_pk_f32_fp8(vB3, true);
    a0 = fmaf(gB3, lo.x, a0); a1 = fmaf(gB3, lo.y, a1);
    a2 = fmaf(gB3, hi.x, a2); a3 = fmaf(gB3, hi.y, a3);
  }
  a0 += __shfl_xor(a0, 16, 64);
  a1 += __shfl_xor(a1, 16, 64);
  a2 += __shfl_xor(a2, 16, 64);
  a3 += __shfl_xor(a3, 16, 64);
  a0 += __shfl_xor(a0, 32, 64);
  a1 += __shfl_xor(a1, 32, 64);
  a2 += __shfl_xor(a2, 32, 64);
  a3 += __shfl_xor(a3, 32, 64);
  unsigned ro = ((unsigned)node << 4) + d;
  if (g == 0) {
    u64 pv = __builtin_nontemporal_load(acc64 + ro);
    unsigned lo32 = (unsigned)pv, hi32 = (unsigned)(pv >> 32);
    float x0 = __uint_as_float(lo32 << 16) + a0;
    float x1 = __uint_as_float(lo32 & 0xffff0000u) + a1;
    float x2 = __uint_as_float(hi32 << 16) + a2;
    float x3 = __uint_as_float(hi32 & 0xffff0000u) + a3;
    __builtin_nontemporal_store(pk4(x0, x1, x2, x3), acc64 + ro);
  } else if (g == 1 && !last) {
    int p = __builtin_amdgcn_cvt_pk_fp8_f32(a0, a1, 0, false);
    p = __builtin_amdgcn_cvt_pk_fp8_f32(a2, a3, p, true);
    nxt[ro] = (unsigned)p;
  }
}

// ---------------- fused post pass: batch_user | batch_item | KL | int_loss ----------------
// Round 15: ui in LDS as bf16 (LDS 42.5->26KB, 3->6 blocks/CU) + paired LDS
// reads + unroll 8 on all shfl loops (batches the ds/bpermute latency that
// made this branch serial: ~120cy per un-batched LDS op).
__global__ __launch_bounds__(256) void k_post(
    const unsigned short* __restrict__ accB,
    const float* __restrict__ user_emb, const float* __restrict__ item_emb,
    const float* __restrict__ eps,
    const float* __restrict__ user_int, const float* __restrict__ item_int,
    const float* __restrict__ lin_w, const float* __restrict__ lin_b,
    const int* __restrict__ users, const int* __restrict__ pos_items,
    const int* __restrict__ neg_items,
    unsigned short* __restrict__ ugen_b, unsigned short* __restrict__ uio_b,
    unsigned short* __restrict__ igen_b, unsigned short* __restrict__ iio_b,
    float* __restrict__ posu, float* __restrict__ posi,
    double* __restrict__ accums) {
  __shared__ unsigned short uib[64 * 130];  // bf16 intent, row-major d x k
  __shared__ float lw[64 * 34];
  __shared__ float lb[64];
  __shared__ double red[8];
  int bid = blockIdx.x;
  int lane = threadIdx.x & 63;
  int wid = threadIdx.x >> 6;
  if (bid < 2048) {
    // ---- batch branch (user: bid<1024, item: bid>=1024) ----
    int isI = bid >> 10;
    int bb = bid & 1023;
    const float* intent = isI ? item_int : user_int;
    for (int i = threadIdx.x; i < 64 * 128; i += 256)
      uib[(i >> 7) * 130 + (i & 127)] = f2b(intent[i]);
    for (int i = threadIdx.x; i < 64 * 32; i += 256)
      lw[(i >> 5) * 34 + (i & 31)] = lin_w[i];
    if (threadIdx.x < 64) lb[threadIdx.x] = lin_b[threadIdx.x];
    __syncthreads();
    int b = (bb << 2) + wid;
    int pi = pos_items[b], ni = neg_items[b];
    int u = isI ? 0 : users[b];
    int row = isI ? (NU + pi) : u;
    float m = b2f(accB[(size_t)row * 64 + lane]);
    int k0 = lane * 2;
    float l0 = 0.f, l1 = 0.f, l2 = 0.f, l3 = 0.f;
#pragma unroll 8
    for (int dd = 0; dd < 64; dd += 2) {
      float md0 = __shfl(m, dd, 64);
      float md1 = __shfl(m, dd + 1, 64);
      unsigned w0 = *(const unsigned*)&uib[dd * 130 + k0];
      unsigned w1 = *(const unsigned*)&uib[(dd + 1) * 130 + k0];
      l0 = fmaf(md0, __uint_as_float(w0 << 16), l0);
      l1 = fmaf(md0, __uint_as_float(w0 & 0xffff0000u), l1);
      l2 = fmaf(md1, __uint_as_float(w1 << 16), l2);
      l3 = fmaf(md1, __uint_as_float(w1 & 0xffff0000u), l3);
    }
    l0 += l2; l1 += l3;
    float mx = wmax(fmaxf(l0, l1));
    float p0 = expf(l0 - mx), p1 = expf(l1 - mx);
    float tot = wsum(p0 + p1);
    p0 /= tot; p1 /= tot;
    float s = 0.f, s2 = 0.f;
#pragma unroll 8
    for (int k = 0; k < 128; k += 2) {
      float pk0 = __shfl(p0, k >> 1, 64);
      float pk1 = __shfl(p1, k >> 1, 64);
      unsigned w = *(const unsigned*)&uib[lane * 130 + k];
      s = fmaf(pk0, __uint_as_float(w << 16), s);
      s2 = fmaf(pk1, __uint_as_float(w & 0xffff0000u), s2);
    }
    s += s2;
    float nrm = sqrtf(wsum(s * s));
    float io = s / nrm;
    (isI ? iio_b : uio_b)[b * 64 + lane] = f2b(io);
    float sp = softplusf(m);
    float sdv = lb[lane] + 1e-8f, sd2 = 0.f;
#pragma unroll
    for (int j = 0; j < 32; j += 2) {
      float sp0 = __shfl(sp, j, 64);
      float sp1 = __shfl(sp, j + 1, 64);
      float2 wv = *(const float2*)&lw[lane * 34 + j];
      sdv = fmaf(sp0, wv.x, sdv);
      sd2 = fmaf(sp1, wv.y, sd2);
    }
    sdv += sd2;
    float ge = m + eps[(size_t)row * 64 + lane] * sdv;
    float gn = sqrtf(wsum(ge * ge));
    float go = ge / gn;
    (isI ? igen_b : ugen_b)[b * 64 + lane] = f2b(go);
    float pd = wsum(go * io);  // InfoNCE positive dot, fused here
    if (lane == 0) (isI ? posi : posu)[b] = pd;
    if (!isI) {
      float pv = b2f(accB[(size_t)(NU + pi) * 64 + lane]);
      float nv = b2f(accB[(size_t)(NU + ni) * 64 + lane]);
      float ps = wsum(m * pv);
      float ns = wsum(m * nv);
      float bpr = softplusf(ns - ps);
      float ue = user_emb[(size_t)u * 64 + lane];
      float es = wsum(ue * ue);
      if (lane == 0) { red[wid] = (double)bpr; red[4 + wid] = (double)es; }
      __syncthreads();
      if (threadIdx.x == 0) {
        atomicAdd(&accums[0], red[0] + red[1] + red[2] + red[3]);
        atomicAdd(&accums[2], red[4] + red[5] + red[6] + red[7]);
      }
    } else {
      float e0 = item_emb[(size_t)pi * 64 + lane];
      float e1 = item_emb[(size_t)ni * 64 + lane];
      float es = wsum(e0 * e0 + e1 * e1);
      if (lane == 0) red[wid] = (double)es;
      __syncthreads();
      if (threadIdx.x == 0) atomicAdd(&accums[2], red[0] + red[1] + red[2] + red[3]);
    }
  } else if (bid < 2048 + 640) {
    // ---- KL branch (MFMA over bf16 acc) ----
    int n = lane & 15, q = lane >> 4;
    bf16x8 B0, B1, B2, B3;
    float lb0, lb1, lb2, lb3;
    {
      const float* w0 = lin_w + (0 * 16 + n) * 32 + q * 8;
      const float* w1 = lin_w + (1 * 16 + n) * 32 + q * 8;
      const float* w2 = lin_w + (2 * 16 + n) * 32 + q * 8;
      const float* w3 = lin_w + (3 * 16 + n) * 32 + q * 8;
#pragma unroll
      for (int j = 0; j < 8; j++) {
        B0[j] = (short)f2b(w0[j]);
        B1[j] = (short)f2b(w1[j]);
        B2[j] = (short)f2b(w2[j]);
        B3[j] = (short)f2b(w3[j]);
      }
      lb0 = lin_b[0 * 16 + n] + 1e-8f;
      lb1 = lin_b[1 * 16 + n] + 1e-8f;
      lb2 = lin_b[2 * 16 + n] + 1e-8f;
      lb3 = lin_b[3 * 16 + n] + 1e-8f;
    }
    const int TI = NT / 16;
    int w0id = (bid - 2048) * 4 + wid;
    int nwv = 640 * 4;
    double dsum = 0.0;
    for (int tile = w0id; tile < TI; tile += nwv) {
      const u64* rp = (const u64*)(accB + (size_t)(tile * 16 + n) * 64 + q * 8);
      u64 A0 = __builtin_nontemporal_load(rp);
      u64 A1 = __builtin_nontemporal_load(rp + 1);
      u64 C0 = __builtin_nontemporal_load(rp + 8);   // +32 dims
      u64 C1 = __builtin_nontemporal_load(rp + 9);
      float av[8], bv[8];
      unp4(A0, av); unp4(A1, av + 4);
      unp4(C0, bv); unp4(C1, bv + 4);
      float msum = 0.f;
#pragma unroll
      for (int j = 0; j < 8; j++) msum += av[j] * av[j] + bv[j] * bv[j];
      bf16x8 Af;
#pragma unroll
      for (int j = 0; j < 8; j++) Af[j] = (short)f2b(softplusf(av[j]));
      f32x4 z = {0.f, 0.f, 0.f, 0.f};
      f32x4 c0 = __builtin_amdgcn_mfma_f32_16x16x32_bf16(Af, B0, z, 0, 0, 0);
      f32x4 c1 = __builtin_amdgcn_mfma_f32_16x16x32_bf16(Af, B1, z, 0, 0, 0);
      f32x4 c2 = __builtin_amdgcn_mfma_f32_16x16x32_bf16(Af, B2, z, 0, 0, 0);
      f32x4 c3 = __builtin_amdgcn_mfma_f32_16x16x32_bf16(Af, B3, z, 0, 0, 0);
      float ksum = 0.f;
#pragma unroll
      for (int r = 0; r < 4; r++) {
        float s0 = c0[r] + lb0, s1 = c1[r] + lb1, s2 = c2[r] + lb2, s3 = c3[r] + lb3;
        ksum += -0.5f * (1.f + 2.f * s0 - __expf(2.f * s0));
        ksum += -0.5f * (1.f + 2.f * s1 - __expf(2.f * s1));
        ksum += -0.5f * (1.f + 2.f * s2 - __expf(2.f * s2));
        ksum += -0.5f * (1.f + 2.f * s3 - __expf(2.f * s3));
      }
      dsum += (double)wsum(ksum + 0.5f * msum);
    }
    if (lane == 0) red[wid] = dsum;
    __syncthreads();
    if (threadIdx.x == 0)
      atomicAdd(&accums[1], red[0] + red[1] + red[2] + red[3]);
  } else {
    // ---- int_loss block ----
    float s = 0.f;
    for (int i = threadIdx.x; i < 64 * 128; i += 256) {
      float a = user_int[i], b = item_int[i];
      s = fmaf(a, a, s);
      s = fmaf(b, b, s);
    }
    s = wsum(s);
    if (lane == 0) red[wid] = (double)s;
    __syncthreads();
    if (threadIdx.x == 0) atomicAdd(&accums[3], red[0] + red[1] + red[2] + red[3]);
  }
}

// ---------------- InfoNCE negatives (bf16 MFMA) ----------------
// Round 15: j split 16-way (grid 64x32 = 2048 blocks, 8/CU) + 2-wide unroll;
// the ticketed last-block combine moved to k_out (its serial atomic-read tail
// cost ~20us inside this dispatch).
__global__ __launch_bounds__(256) void k_nce(
    const unsigned short* __restrict__ e1u, const unsigned short* __restrict__ e2u,
    const unsigned short* __restrict__ e1i, const unsigned short* __restrict__ e2i,
    float* __restrict__ negu, float* __restrict__ negi) {
  int pr = blockIdx.y >> 4, jq = blockIdx.y & 15;
  const unsigned short* e1 = pr ? e1i : e1u;
  const unsigned short* e2 = pr ? e2i : e2u;
  float* nego = pr ? negi : negu;
  int wid = threadIdx.x >> 6, lane = threadIdx.x & 63;
  int q = lane >> 4, n = lane & 15;
  int i0 = blockIdx.x * 64 + wid * 16;
  const bf16x8* arow = (const bf16x8*)(e1 + (size_t)(i0 + n) * 64 + q * 8);
  bf16x8 a0 = arow[0];
  bf16x8 a1 = arow[4];
  f32x4 accv = {0.f, 0.f, 0.f, 0.f};
  int j0 = jq * 256;
  for (int jt = 0; jt < 16; jt += 2) {
    const bf16x8* br0 = (const bf16x8*)(e2 + (size_t)(j0 + jt * 16 + n) * 64 + q * 8);
    const bf16x8* br1 = (const bf16x8*)(e2 + (size_t)(j0 + (jt + 1) * 16 + n) * 64 + q * 8);
    bf16x8 b0 = br0[0];
    bf16x8 b1 = br0[4];
    bf16x8 b2 = br1[0];
    bf16x8 b3 = br1[4];
    f32x4 c = {0.f, 0.f, 0.f, 0.f};
    f32x4 c2 = {0.f, 0.f, 0.f, 0.f};
    c = __builtin_amdgcn_mfma_f32_16x16x32_bf16(a0, b0, c, 0, 0, 0);
    c = __builtin_amdgcn_mfma_f32_16x16x32_bf16(a1, b1, c, 0, 0, 0);
    c2 = __builtin_amdgcn_mfma_f32_16x16x32_bf16(a0, b2, c2, 0, 0, 0);
    c2 = __builtin_amdgcn_mfma_f32_16x16x32_bf16(a1, b3, c2, 0, 0, 0);
#pragma unroll
    for (int r = 0; r < 4; r++)
      accv[r] += __expf(5.0f * c[r]) + __expf(5.0f * c2[r]);
  }
#pragma unroll
  for (int o = 1; o < 16; o <<= 1) {
#pragma unroll
    for (int r = 0; r < 4; r++) accv[r] += __shfl_xor(accv[r], o, 64);
  }
  if (n == 0) {
#pragma unroll
    for (int r = 0; r < 4; r++) atomicAdd(&nego[i0 + q * 4 + r], accv[r]);
  }
}

// final combine: nce log-sum + output assembly (1 block)
__global__ __launch_bounds__(256) void k_out(
    const float* __restrict__ posu, const float* __restrict__ posi,
    const float* __restrict__ negu, const float* __restrict__ negi,
    const double* __restrict__ accums, float* __restrict__ out) {
  __shared__ double redd[4];
  double cl = 0.0;
  for (int i = threadIdx.x; i < 2 * BB; i += 256) {
    int pr = i >> 12, idx = i & (BB - 1);
    float ng = pr ? negi[idx] : negu[idx];
    float dt = pr ? posi[idx] : posu[idx];
    float pos = expf(5.0f * dt);
    cl += (double)(-logf(pos / (ng + 1e-8f) + 1e-8f));
  }
#pragma unroll
  for (int o = 32; o > 0; o >>= 1) cl += __shfl_xor(cl, o, 64);
  int lane = threadIdx.x & 63, wid = threadIdx.x >> 6;
  if (lane == 0) redd[wid] = cl;
  __syncthreads();
  if (threadIdx.x == 0) {
    double cls = redd[0] + redd[1] + redd[2] + redd[3];
    double bpr = accums[0] / (double)BB;
    double kl = 0.01 * accums[1] / (double)NT;
    out[0] = (float)(bpr + kl);
    out[1] = (float)(0.1 * cls / (double)BB);
    out[2] = (float)(1e-5 * accums[2]);
    out[3] = (float)(1e-5 * accums[3]);
  }
}

extern "C" void kernel_launch(void* const* d_in, const int* in_sizes, int n_in,
                              void* d_out, int out_size, void* d_ws, size_t ws_size,
                              hipStream_t stream) {
  const float* user_emb = (const float*)d_in[0];
  const float* item_emb = (const float*)d_in[1];
  const float* user_int = (const float*)d_in[2];
  const float* item_int = (const float*)d_in[3];
  const float* lin_w = (const float*)d_in[4];
  const float* lin_b = (const float*)d_in[5];
  const float* eps = (const float*)d_in[6];
  const int* h_list = (const int*)d_in[7];
  const int* t_list = (const int*)d_in[8];
  const int* users = (const int*)d_in[9];
  const int* pos_items = (const int*)d_in[10];
  const int* neg_items = (const int*)d_in[11];
  float* out = (float*)d_out;
  const int E = in_sizes[7];

  char* ws = (char*)d_ws;
  size_t off = 0;
  auto take = [&](size_t bytes) -> char* {
    char* p = ws + off;
    off = (off + bytes + 255) & ~(size_t)255;
    return p;
  };
  int* row_ptr = (int*)take((size_t)(NT + 1) * 4);
  float* d_inv = (float*)take((size_t)NT * 4);
  int* rloc_g = (int*)take((size_t)NT * 4);
  int* cnt_chunk = (int*)take((size_t)NBUCK * NCH * 1024 * 4);
  int* gcur = (int*)take(NBUCK * 4);
  int* btot = (int*)take(NBUCK * 4);
  uint2* edges = (uint2*)take((size_t)E * 8);
  unsigned* bufA = (unsigned*)take((size_t)NT * 16 * 4);  // fp8 rows (16 dwords)
  unsigned* bufB = (unsigned*)take((size_t)NT * 16 * 4);
  // accB (bf16 rows, 19.2MB) shares a region with part (28.9MB): part's last
  // read is k_fill2; accB is first written in k_init (which runs after).
  unsigned short* accB = (unsigned short*)take((size_t)NBUCK * BCAP * 8);
  unsigned short* ugen_b = (unsigned short*)take((size_t)BB * 64 * 2);
  unsigned short* igen_b = (unsigned short*)take((size_t)BB * 64 * 2);
  unsigned short* uio_b = (unsigned short*)take((size_t)BB * 64 * 2);
  unsigned short* iio_b = (unsigned short*)take((size_t)BB * 64 * 2);
  float* posu = (float*)take((size_t)BB * 4);
  float* posi = (float*)take((size_t)BB * 4);
  float* negu = (float*)take((size_t)BB * 4);
  float* negi = (float*)take((size_t)BB * 4);
  double* accums = (double*)take(64);
  if (off > ws_size) return;
  uint2* part = (uint2*)accB;
  u64* acc64 = (u64*)accB;

  k_zero<<<1, 256, 0, stream>>>(gcur, negu, negi, accums);

  int gridP = (E + 4095) / 4096;
  k_part<<<gridP, 256, 0, stream>>>(h_list, t_list, gcur, part, E);
  k_count2<<<dim3(NBUCK, NCH), 256, 0, stream>>>(part, gcur, cnt_chunk);
  k_node<<<NBUCK, 256, 0, stream>>>(cnt_chunk, rloc_g, d_inv, btot);
  k_fill2<<<dim3(NBUCK, NCH), 256, 0, stream>>>(part, gcur, cnt_chunk, rloc_g,
                                                btot, d_inv, edges, row_ptr);

  int nU4 = NU * 16, nTot4 = NT * 16;
  k_init<<<(nTot4 + 255) / 256, 256, 0, stream>>>((const float4*)user_emb,
                                                  (const float4*)item_emb, bufA,
                                                  acc64, nU4, nTot4);
  int gridAgg = NT / 4;
  k_agg<<<gridAgg, 256, 0, stream>>>(row_ptr, edges, bufA, bufB, acc64, 0);
  k_agg<<<gridAgg, 256, 0, stream>>>(row_ptr, edges, bufB, bufA, acc64, 0);
  k_agg<<<gridAgg, 256, 0, stream>>>(row_ptr, edges, bufA, bufB, acc64, 1);

  k_post<<<2048 + 640 + 1, 256, 0, stream>>>(accB, user_emb, item_emb, eps,
                                             user_int, item_int, lin_w, lin_b,
                                             users, pos_items, neg_items,
                                             ugen_b, uio_b, igen_b, iio_b,
                                             posu, posi, accums);
  k_nce<<<dim3(64, 32), 256, 0, stream>>>(ugen_b, uio_b, igen_b, iio_b,
                                          negu, negi);
  k_out<<<1, 256, 0, stream>>>(posu, posi, negu, negi, accums, out);
}